// Round 2
// baseline (1270.752 us; speedup 1.0000x reference)
//
#include <hip/hip_runtime.h>
#include <hip/hip_bf16.h>

#define B_ 64
#define N_ 4096
#define D_ 256
#define S_ 8
#define NH_ 8
#define DK_ 32
#define ITERS_ 3
#define MLPH_ 512
#define EPS_ 1e-5f
#define M_ (B_*N_)          // 262144 rows of x
#define NEG_BIG_ -3.0e38f   // finite sentinel: exp(NEG_BIG_-x) underflows to 0.f
#define NSPLIT_ 4           // attention N-partitions per (b,h)

typedef unsigned short u16;
typedef short bf16x8 __attribute__((ext_vector_type(8)));
typedef float f32x4 __attribute__((ext_vector_type(4)));

__device__ __forceinline__ u16 f2bf(float f){
  unsigned int x = __float_as_uint(f);
  return (u16)((x + 0x7fffu + ((x >> 16) & 1u)) >> 16);   // RNE
}
__device__ __forceinline__ unsigned int pkbf(float a, float b){
  return (unsigned int)f2bf(a) | ((unsigned int)f2bf(b) << 16);
}

// ---------------------------------------------------------------- prep
__global__ void prep_kernel(const float* __restrict__ wk, const float* __restrict__ wv,
                            const float* __restrict__ wih, const float* __restrict__ whh,
                            u16* __restrict__ wkvT, float* __restrict__ wihT,
                            float* __restrict__ whhT){
  int idx = blockIdx.x * 256 + threadIdx.x;
  if(idx < 512*256){
    int n = idx >> 8, k = idx & 255;
    float v = (n < 256) ? wk[k*256 + n] : wv[k*256 + (n-256)];
    wkvT[n*256 + k] = f2bf(v);
    return;
  }
  int i2 = idx - 512*256;
  if(i2 < 196608){           // w_ihT
    int d = i2 / 768, j = i2 - d*768;
    wihT[i2] = wih[j*256 + d];
    return;
  }
  int i3 = i2 - 196608;
  if(i3 < 196608){           // w_hhT
    int d = i3 / 768, j = i3 - d*768;
    whhT[i3] = whh[j*256 + d];
  }
}

// ---------------------------------------------------------------- slot init
__global__ void init_slots(const float* __restrict__ mu, const float* __restrict__ lsig,
                           const float* __restrict__ noise, float* __restrict__ slots){
  int idx = blockIdx.x * 256 + threadIdx.x;   // < 131072
  int d = idx & 255;
  slots[idx] = mu[d] + __expf(lsig[d]) * noise[idx];
}

// ---------------------------------------------------------------- LN(inputs) -> bf16
__global__ __launch_bounds__(256) void ln_kernel(const float* __restrict__ inp,
                                                 const float* __restrict__ g,
                                                 const float* __restrict__ b,
                                                 u16* __restrict__ xb){
  int wave = threadIdx.x >> 6, lane = threadIdx.x & 63;
  int row = blockIdx.x * 4 + wave;
  float4 v = *(const float4*)(inp + (size_t)row*D_ + lane*4);
  float s  = v.x+v.y+v.z+v.w;
  float ss = v.x*v.x + v.y*v.y + v.z*v.z + v.w*v.w;
  #pragma unroll
  for(int o=32;o>=1;o>>=1){ s += __shfl_xor(s,o,64); ss += __shfl_xor(ss,o,64); }
  float mean = s * (1.f/D_);
  float var  = ss * (1.f/D_) - mean*mean;
  float rstd = rsqrtf(var + EPS_);
  float4 gg = *(const float4*)(g + lane*4);
  float4 bb = *(const float4*)(b + lane*4);
  ushort4 o4;
  o4.x = f2bf((v.x-mean)*rstd*gg.x + bb.x);
  o4.y = f2bf((v.y-mean)*rstd*gg.y + bb.y);
  o4.z = f2bf((v.z-mean)*rstd*gg.z + bb.z);
  o4.w = f2bf((v.w-mean)*rstd*gg.w + bb.w);
  *(ushort4*)(xb + (size_t)row*D_ + lane*4) = o4;
}

// ---------------------------------------------------------------- K/V projection GEMM
// K stored row-major [bh][n][32]; V stored TRANSPOSED [bh][d][n] for MFMA attention.
// 2-phase reg-staged pipeline: chunk k+1 global loads issued before chunk k compute.
// V epilogue: LDS-transpose (two 128-col passes reusing Bs) -> 256B-contiguous stores.
__global__ __launch_bounds__(512) void kv_gemm(const u16* __restrict__ xb,
                                               const u16* __restrict__ wkvT,
                                               const float* __restrict__ bk,
                                               const float* __restrict__ bv,
                                               u16* __restrict__ Kp, u16* __restrict__ Vp){
  __shared__ u16 As[128*72];
  __shared__ u16 Bs[256*72];
  int rt = blockIdx.x, ct = blockIdx.y;
  int tid = threadIdx.x;
  int w = tid >> 6, lane = tid & 63;
  int wm = w >> 2, wn = w & 3;           // 2x4 waves of 64x64
  int lr = lane & 15, quad = lane >> 4;
  f32x4 zf = {0.f,0.f,0.f,0.f};
  f32x4 acc[4][4];
  #pragma unroll
  for(int mt=0;mt<4;mt++)
    #pragma unroll
    for(int nt=0;nt<4;nt++) acc[mt][nt] = zf;

  int ar = tid >> 3, ac8 = (tid & 7) * 8;            // staging coords
  const u16* agp = xb   + (size_t)(rt*128)*256;
  const u16* bgp = wkvT + (size_t)(ct*256)*256;

  uint4 ra[2], rb[4];
  #pragma unroll
  for(int p=0;p<2;p++) ra[p] = *(const uint4*)(agp + (size_t)(ar + p*64)*256 + ac8);
  #pragma unroll
  for(int p=0;p<4;p++) rb[p] = *(const uint4*)(bgp + (size_t)(ar + p*64)*256 + ac8);

  for(int kk=0; kk<4; kk++){
    __syncthreads();
    #pragma unroll
    for(int p=0;p<2;p++) *(uint4*)(As + (ar + p*64)*72 + ac8) = ra[p];
    #pragma unroll
    for(int p=0;p<4;p++) *(uint4*)(Bs + (ar + p*64)*72 + ac8) = rb[p];
    __syncthreads();
    if(kk < 3){                                       // prefetch next chunk
      #pragma unroll
      for(int p=0;p<2;p++) ra[p] = *(const uint4*)(agp + (size_t)(ar + p*64)*256 + (kk+1)*64 + ac8);
      #pragma unroll
      for(int p=0;p<4;p++) rb[p] = *(const uint4*)(bgp + (size_t)(ar + p*64)*256 + (kk+1)*64 + ac8);
    }
    #pragma unroll
    for(int k32=0;k32<64;k32+=32){
      bf16x8 a[4], b[4];
      #pragma unroll
      for(int mt=0;mt<4;mt++)
        a[mt] = *(const bf16x8*)(As + (wm*64 + mt*16 + lr)*72 + k32 + quad*8);
      #pragma unroll
      for(int nt=0;nt<4;nt++)
        b[nt] = *(const bf16x8*)(Bs + (wn*64 + nt*16 + lr)*72 + k32 + quad*8);
      #pragma unroll
      for(int mt=0;mt<4;mt++)
        #pragma unroll
        for(int nt=0;nt<4;nt++)
          acc[mt][nt] = __builtin_amdgcn_mfma_f32_16x16x32_bf16(a[mt], b[nt], acc[mt][nt], 0,0,0);
    }
  }

  int bb = rt >> 5;                 // batch index (128 rows never straddle a b)
  int n0 = (rt & 31) * 128;         // n offset within batch
  if(ct == 0){
    // K epilogue: direct stores, lanes cover 32 consecutive d per (h,n)
    #pragma unroll
    for(int mt=0;mt<4;mt++){
      #pragma unroll
      for(int nt=0;nt<4;nt++){
        int gc = wn*64 + nt*16 + lr;          // 0..255
        int h = gc >> 5, d = gc & 31;
        float bias = bk[gc];
        int r0 = wm*64 + mt*16 + quad*4;
        #pragma unroll
        for(int i=0;i<4;i++){
          int n = n0 + r0 + i;
          Kp[((size_t)(bb*8 + h)*4096 + n)*32 + d] = f2bf(acc[mt][nt][i] + bias);
        }
      }
    }
  } else {
    // V epilogue: transpose via LDS (reuse Bs), two 128-col passes
    u16* Ts = Bs;                              // [128 cols][136] padded rows
    #pragma unroll
    for(int h2=0; h2<2; h2++){
      __syncthreads();                         // Bs reads done / prev pass done
      if((wn >> 1) == h2){
        #pragma unroll
        for(int mt=0;mt<4;mt++){
          #pragma unroll
          for(int nt=0;nt<4;nt++){
            int col = wn*64 + nt*16 + lr;      // 0..255 (c2 for bias)
            int lc  = col & 127;
            float bias = bv[col];
            int r0 = wm*64 + mt*16 + quad*4;
            #pragma unroll
            for(int i=0;i<4;i++)
              Ts[lc*136 + r0 + i] = f2bf(acc[mt][nt][i] + bias);
          }
        }
      }
      __syncthreads();
      {
        int tcol = tid >> 2, seg = tid & 3;    // 128 cols x 4 segs of 32 n
        int gcol = h2*128 + tcol;
        int h = gcol >> 5, d = gcol & 31;
        u16* dst = Vp + ((size_t)(bb*8 + h)*32 + d)*4096 + n0 + seg*32;
        const u16* src = Ts + tcol*136 + seg*32;
        #pragma unroll
        for(int j=0;j<4;j++)
          *(uint4*)(dst + j*8) = *(const uint4*)(src + j*8);
      }
    }
  }
}

// ---------------------------------------------------------------- LN(slots)+Q proj
__global__ __launch_bounds__(256) void qproj(const float* __restrict__ slots,
                                             const float* __restrict__ g,
                                             const float* __restrict__ b,
                                             const float* __restrict__ wq,
                                             const float* __restrict__ bq,
                                             float* __restrict__ Q){
  __shared__ float sp[256];
  __shared__ float red[8];
  int r = blockIdx.x, t = threadIdx.x;
  float v = slots[r*256 + t];
  float s1 = v, s2 = v*v;
  #pragma unroll
  for(int o=32;o>=1;o>>=1){ s1 += __shfl_xor(s1,o,64); s2 += __shfl_xor(s2,o,64); }
  int wv_ = t >> 6, lane = t & 63;
  if(lane==0){ red[wv_] = s1; red[4+wv_] = s2; }
  __syncthreads();
  float fs1 = red[0]+red[1]+red[2]+red[3];
  float fs2 = red[4]+red[5]+red[6]+red[7];
  float mean = fs1*(1.f/256.f);
  float var  = fs2*(1.f/256.f) - mean*mean;
  float rstd = rsqrtf(var + EPS_);
  sp[t] = (v - mean)*rstd*g[t] + b[t];
  __syncthreads();
  float acc = bq[t];
  for(int d=0; d<256; d++) acc = fmaf(sp[d], wq[d*256 + t], acc);
  int b_ = r >> 3, s_ = r & 7;
  int h = t >> 5, d_ = t & 31;
  Q[((b_*8 + h)*8 + s_)*32 + d_] = acc;
}

// ---------------------------------------------------------------- attention (MFMA, slot-shared)
// grid (512, NSPLIT_); block = 256 (4 waves). Block = (b,h); each wave owns a
// 256-row slice of its 1024-row split and computes ALL 8 slots via MFMA:
//   scores^T: C1[n16][s] = mfma(A=K rows [n x d], B=Q^T [d x s])
//   out^T   : C2[d16][s] = mfma(A=V^T rows [d x n], B=P [n x s])
// Softmax state lives at s = lane&15 in both C1 and C2 layouts -> no cross-lane
// moves for m/l/corr. P is repacked C1->B via 4 packs + 8 shuffles + 4 selects.
// 4 wave-partials merged in LDS -> same Pml/Po format as before (NSPLIT_ parts).
__global__ __launch_bounds__(256) void attn_part(const float* __restrict__ Qw,
                                                 const u16* __restrict__ Kp,
                                                 const u16* __restrict__ Vp,
                                                 float2* __restrict__ Pml,
                                                 float* __restrict__ Po){
  const int bh = blockIdx.x, sp_ = blockIdx.y;
  const int w = threadIdx.x >> 6, lane = threadIdx.x & 63;
  const int c = lane & 15, q = lane >> 4;
  const float scale = 0.17677669529663687f;   // 1/sqrt(32)

  __shared__ float oW[4][8][32];
  __shared__ float mW[4][8], lW[4][8];

  // B1 fragment: Q^T, lane holds Q[s=c][d=8q+e]; zeros for padded slots c>=8
  bf16x8 qf;
  {
    union { u16 u[8]; bf16x8 v; } qq;
    if(c < 8){
      const float4* qp = (const float4*)(Qw + ((size_t)bh*8 + c)*32 + q*8);
      float4 v0 = qp[0], v1 = qp[1];
      qq.u[0]=f2bf(v0.x); qq.u[1]=f2bf(v0.y); qq.u[2]=f2bf(v0.z); qq.u[3]=f2bf(v0.w);
      qq.u[4]=f2bf(v1.x); qq.u[5]=f2bf(v1.y); qq.u[6]=f2bf(v1.z); qq.u[7]=f2bf(v1.w);
    } else {
      #pragma unroll
      for(int e=0;e<8;e++) qq.u[e]=0;
    }
    qf = qq.v;
  }

  const int row0 = sp_*(N_/NSPLIT_) + w*(N_/NSPLIT_/4);     // 256-row sub-slice
  const u16* kb = Kp + (size_t)bh*(N_*DK_) + (size_t)row0*DK_;  // K[n][d]
  const u16* vt = Vp + (size_t)bh*(N_*DK_) + row0;              // V^T[d][n]

  float m = NEG_BIG_, l = 0.f;
  f32x4 acc2[2] = {{0.f,0.f,0.f,0.f},{0.f,0.f,0.f,0.f}};
  const int La = c + 32*(q&1);     // shuffle source lanes for P repack
  const int Lb = La + 16;
  const int thi = q >> 1;

  #pragma unroll 2
  for(int ch=0; ch<8; ch++){                 // 8 chunks of 32 rows
    // A1 fragments: K[row0+ch*32+16t+c][8q..8q+7]  (b128 each)
    bf16x8 kf0 = *(const bf16x8*)(kb + (size_t)(ch*32 +      c)*DK_ + q*8);
    bf16x8 kf1 = *(const bf16x8*)(kb + (size_t)(ch*32 + 16 + c)*DK_ + q*8);
    // A2 fragments: V^T[16t+c][row0+ch*32+8q .. +7]  (b128 each)
    bf16x8 vf0 = *(const bf16x8*)(vt + (size_t)(     c)*N_ + ch*32 + q*8);
    bf16x8 vf1 = *(const bf16x8*)(vt + (size_t)(16 + c)*N_ + ch*32 + q*8);

    f32x4 s0 = {0.f,0.f,0.f,0.f}, s1 = {0.f,0.f,0.f,0.f};
    s0 = __builtin_amdgcn_mfma_f32_16x16x32_bf16(kf0, qf, s0, 0,0,0);
    s1 = __builtin_amdgcn_mfma_f32_16x16x32_bf16(kf1, qf, s1, 0,0,0);

    // lane holds scores for s=c at n = ch*32 + 16t + 4q + r
    float p[8];
    #pragma unroll
    for(int r=0;r<4;r++){ p[r] = s0[r]*scale; p[4+r] = s1[r]*scale; }
    float cm = p[0];
    #pragma unroll
    for(int i=1;i<8;i++) cm = fmaxf(cm, p[i]);
    cm = fmaxf(cm, __shfl_xor(cm, 16, 64));
    cm = fmaxf(cm, __shfl_xor(cm, 32, 64));
    float nm = fmaxf(m, cm);
    float corr = __expf(m - nm);
    m = nm;
    float ps = 0.f;
    #pragma unroll
    for(int i=0;i<8;i++){ p[i] = __expf(p[i] - nm); ps += p[i]; }
    ps += __shfl_xor(ps, 16, 64);
    ps += __shfl_xor(ps, 32, 64);
    l = l*corr + ps;
    #pragma unroll
    for(int r=0;r<4;r++){ acc2[0][r] *= corr; acc2[1][r] *= corr; }

    // repack P (C1 layout) -> B2 fragment: lane needs P[n=8q+e][s=c]
    unsigned int u0 = pkbf(p[0],p[1]), u1 = pkbf(p[2],p[3]);
    unsigned int u2 = pkbf(p[4],p[5]), u3 = pkbf(p[6],p[7]);
    unsigned int a0 = (unsigned int)__shfl((int)u0, La, 64);
    unsigned int a1 = (unsigned int)__shfl((int)u1, La, 64);
    unsigned int a2 = (unsigned int)__shfl((int)u2, La, 64);
    unsigned int a3 = (unsigned int)__shfl((int)u3, La, 64);
    unsigned int b0 = (unsigned int)__shfl((int)u0, Lb, 64);
    unsigned int b1 = (unsigned int)__shfl((int)u1, Lb, 64);
    unsigned int b2 = (unsigned int)__shfl((int)u2, Lb, 64);
    unsigned int b3 = (unsigned int)__shfl((int)u3, Lb, 64);
    union { unsigned int wu[4]; bf16x8 v; } pf;
    pf.wu[0] = thi ? a2 : a0;
    pf.wu[1] = thi ? a3 : a1;
    pf.wu[2] = thi ? b2 : b0;
    pf.wu[3] = thi ? b3 : b1;

    acc2[0] = __builtin_amdgcn_mfma_f32_16x16x32_bf16(vf0, pf.v, acc2[0], 0,0,0);
    acc2[1] = __builtin_amdgcn_mfma_f32_16x16x32_bf16(vf1, pf.v, acc2[1], 0,0,0);
  }

  // wave partials -> LDS.  acc2[t][r] = out^T[d=16t+4q+r][s=c] (unnormalized)
  if(c < 8){
    #pragma unroll
    for(int t=0;t<2;t++)
      #pragma unroll
      for(int r=0;r<4;r++)
        oW[w][c][16*t + 4*q + r] = acc2[t][r];
    if(q == 0){ mW[w][c] = m; lW[w][c] = l; }
  }
  __syncthreads();
  {
    int s = threadIdx.x >> 5, d = threadIdx.x & 31;   // 8 x 32 = 256 threads
    float M = fmaxf(fmaxf(mW[0][s], mW[1][s]), fmaxf(mW[2][s], mW[3][s]));
    float L = 0.f, O = 0.f;
    #pragma unroll
    for(int k=0;k<4;k++){
      float e = __expf(mW[k][s] - M);
      L += lW[k][s]*e;
      O += oW[k][s][d]*e;
    }
    Po[((size_t)(bh*8 + s)*NSPLIT_ + sp_)*32 + d] = O;   // unnormalized
    if(d == 0) Pml[(bh*8 + s)*NSPLIT_ + sp_] = make_float2(M, L);
  }
}

// ---------------------------------------------------------------- merge split partials -> Ow
// one thread per (row, d): row = (bh*8+s) in [0,4096), d in [0,32)
__global__ __launch_bounds__(256) void attn_merge(const float2* __restrict__ Pml,
                                                  const float* __restrict__ Po,
                                                  float* __restrict__ Ow){
  int gid = blockIdx.x * 256 + threadIdx.x;   // < 131072
  int row = gid >> 5, d = gid & 31;
  float2 ml[NSPLIT_];
  #pragma unroll
  for(int k=0;k<NSPLIT_;k++) ml[k] = Pml[row*NSPLIT_ + k];
  float M = ml[0].x;
  #pragma unroll
  for(int k=1;k<NSPLIT_;k++) M = fmaxf(M, ml[k].x);
  float L = 0.f, o = 0.f;
  #pragma unroll
  for(int k=0;k<NSPLIT_;k++){
    float e = __expf(ml[k].x - M);
    L += ml[k].y * e;
    o += Po[(size_t)(row*NSPLIT_ + k)*32 + d] * e;
  }
  Ow[row*32 + d] = o / L;
}

// ---------------------------------------------------------------- out-proj + GRU + LN + MLP
__global__ __launch_bounds__(256) void gru_mlp(const float* __restrict__ Ain,
    const float* __restrict__ slots_in,
    const float* __restrict__ wo,  const float* __restrict__ bo,
    const float* __restrict__ wihT,const float* __restrict__ bih,
    const float* __restrict__ whhT,const float* __restrict__ bhh,
    const float* __restrict__ w1,  const float* __restrict__ b1,
    const float* __restrict__ w2,  const float* __restrict__ b2,
    const float* __restrict__ gm,  const float* __restrict__ bm,
    float* __restrict__ slots_out){
  __shared__ float xr[4][256], hr[4][256], o2[4][256], hnew[4][256], hid[4][512];
  __shared__ float red[4][8];
  int t = threadIdx.x, r0 = blockIdx.x*4;
  int wv_ = t >> 6, lane = t & 63;
  #pragma unroll
  for(int rr=0;rr<4;rr++){
    int r = r0+rr, b_ = r>>3, s_ = r&7;
    int h = t>>5, d = t&31;
    xr[rr][t] = Ain[((b_*8 + h)*8 + s_)*32 + d];   // un-transpose heads
    hr[rr][t] = slots_in[r*256 + t];
  }
  __syncthreads();
  { // out2 = xr @ wo + bo
    float a0=0,a1=0,a2=0,a3=0;
    for(int d=0; d<256; d++){
      float w = wo[d*256 + t];
      a0 = fmaf(xr[0][d],w,a0); a1 = fmaf(xr[1][d],w,a1);
      a2 = fmaf(xr[2][d],w,a2); a3 = fmaf(xr[3][d],w,a3);
    }
    float bv = bo[t];
    o2[0][t]=a0+bv; o2[1][t]=a1+bv; o2[2][t]=a2+bv; o2[3][t]=a3+bv;
  }
  __syncthreads();
  { // GRU gates
    float ir[4]={}, iz[4]={}, inn[4]={}, hrr[4]={}, hz[4]={}, hn[4]={};
    for(int d=0; d<256; d++){
      float wi0 = wihT[d*768 + t], wi1 = wihT[d*768 + 256 + t], wi2 = wihT[d*768 + 512 + t];
      float wh0 = whhT[d*768 + t], wh1 = whhT[d*768 + 256 + t], wh2 = whhT[d*768 + 512 + t];
      #pragma unroll
      for(int rr=0;rr<4;rr++){
        float xo = o2[rr][d], hh = hr[rr][d];
        ir[rr]  = fmaf(xo,wi0,ir[rr]);  iz[rr] = fmaf(xo,wi1,iz[rr]);  inn[rr] = fmaf(xo,wi2,inn[rr]);
        hrr[rr] = fmaf(hh,wh0,hrr[rr]); hz[rr] = fmaf(hh,wh1,hz[rr]);  hn[rr]  = fmaf(hh,wh2,hn[rr]);
      }
    }
    float bi0 = bih[t], bi1 = bih[256+t], bi2 = bih[512+t];
    float bh0 = bhh[t], bh1 = bhh[256+t], bh2 = bhh[512+t];
    #pragma unroll
    for(int rr=0;rr<4;rr++){
      float rg = 1.f/(1.f + __expf(-(ir[rr]+bi0 + hrr[rr]+bh0)));
      float zg = 1.f/(1.f + __expf(-(iz[rr]+bi1 + hz[rr]+bh1)));
      float ng = tanhf(inn[rr]+bi2 + rg*(hn[rr]+bh2));
      hnew[rr][t] = (1.f - zg)*ng + zg*hr[rr][t];
    }
  }
  __syncthreads();
  // LN(hnew) per row -> m stored in xr (xr is dead)
  #pragma unroll
  for(int rr=0;rr<4;rr++){
    float v = hnew[rr][t];
    float s1=v, s2=v*v;
    #pragma unroll
    for(int o=32;o>=1;o>>=1){ s1 += __shfl_xor(s1,o,64); s2 += __shfl_xor(s2,o,64); }
    if(lane==0){ red[rr][wv_]=s1; red[rr][4+wv_]=s2; }
  }
  __syncthreads();
  {
    float gmt = gm[t], bmt = bm[t];
    #pragma unroll
    for(int rr=0;rr<4;rr++){
      float fs1 = red[rr][0]+red[rr][1]+red[rr][2]+red[rr][3];
      float fs2 = red[rr][4]+red[rr][5]+red[rr][6]+red[rr][7];
      float mean = fs1*(1.f/256.f);
      float var  = fs2*(1.f/256.f) - mean*mean;
      float rstd = rsqrtf(var + EPS_);
      xr[rr][t] = (hnew[rr][t]-mean)*rstd*gmt + bmt;
    }
  }
  __syncthreads();
  { // hid = relu(m @ w1 + b1)
    float c0[4]={}, c1[4]={};
    for(int d=0; d<256; d++){
      float wA = w1[d*512 + t], wB = w1[d*512 + 256 + t];
      #pragma unroll
      for(int rr=0;rr<4;rr++){ float mv = xr[rr][d]; c0[rr]=fmaf(mv,wA,c0[rr]); c1[rr]=fmaf(mv,wB,c1[rr]); }
    }
    float b1a = b1[t], b1b = b1[256+t];
    #pragma unroll
    for(int rr=0;rr<4;rr++){
      hid[rr][t]     = fmaxf(c0[rr]+b1a, 0.f);
      hid[rr][t+256] = fmaxf(c1[rr]+b1b, 0.f);
    }
  }
  __syncthreads();
  { // slots_out = hnew + hid @ w2 + b2
    float a[4]={};
    for(int k=0;k<512;k++){
      float w = w2[k*256 + t];
      #pragma unroll
      for(int rr=0;rr<4;rr++) a[rr] = fmaf(hid[rr][k], w, a[rr]);
    }
    float b2t = b2[t];
    #pragma unroll
    for(int rr=0;rr<4;rr++){
      int r = r0+rr;
      slots_out[r*256 + t] = hnew[rr][t] + a[rr] + b2t;
    }
  }
}

// ----------------------------------------------------------------
extern "C" void kernel_launch(void* const* d_in, const int* in_sizes, int n_in,
                              void* d_out, int out_size, void* d_ws, size_t ws_size,
                              hipStream_t stream){
  const float* inputs = (const float*)d_in[0];
  const float* noise  = (const float*)d_in[1];
  const float* mu     = (const float*)d_in[2];
  const float* lsig   = (const float*)d_in[3];
  const float* wq  = (const float*)d_in[4];  const float* bq  = (const float*)d_in[5];
  const float* wk  = (const float*)d_in[6];  const float* bk  = (const float*)d_in[7];
  const float* wv  = (const float*)d_in[8];  const float* bv  = (const float*)d_in[9];
  const float* wo  = (const float*)d_in[10]; const float* bo  = (const float*)d_in[11];
  const float* wih = (const float*)d_in[12]; const float* bih = (const float*)d_in[13];
  const float* whh = (const float*)d_in[14]; const float* bhh = (const float*)d_in[15];
  const float* w1  = (const float*)d_in[16]; const float* b1  = (const float*)d_in[17];
  const float* w2  = (const float*)d_in[18]; const float* b2  = (const float*)d_in[19];
  const float* g_in= (const float*)d_in[20]; const float* b_in= (const float*)d_in[21];
  const float* g_sl= (const float*)d_in[22]; const float* b_sl= (const float*)d_in[23];
  const float* g_ml= (const float*)d_in[24]; const float* b_ml= (const float*)d_in[25];

  const size_t sz_big = (size_t)M_ * D_ * 2;   // 134,217,728 B each
  size_t need = 3*sz_big + 512*256*2 + 2*(256*768*4) + 3*(512*256*4)
              + 4096*NSPLIT_*8 + (size_t)4096*NSPLIT_*32*4;
  if(ws_size < need) return;

  char* p = (char*)d_ws;
  u16*   xb   = (u16*)p;   p += sz_big;
  u16*   Kp   = (u16*)p;   p += sz_big;
  u16*   Vp   = (u16*)p;   p += sz_big;      // holds V^T [bh][d][n]
  u16*   wkvT = (u16*)p;   p += 512*256*2;
  float* wihT = (float*)p; p += 256*768*4;
  float* whhT = (float*)p; p += 256*768*4;
  float* slots= (float*)p; p += 512*256*4;
  float* Qw   = (float*)p; p += 512*256*4;
  float* Ow   = (float*)p; p += 512*256*4;
  float2* Pml = (float2*)p; p += 4096*NSPLIT_*8;
  float* Po   = (float*)p;  p += (size_t)4096*NSPLIT_*32*4;

  prep_kernel<<<2048, 256, 0, stream>>>(wk, wv, wih, whh, wkvT, wihT, whhT);
  init_slots <<<512, 256, 0, stream>>>(mu, lsig, noise, slots);
  ln_kernel  <<<M_/4, 256, 0, stream>>>(inputs, g_in, b_in, xb);
  kv_gemm    <<<dim3(M_/128, 2), 512, 0, stream>>>(xb, wkvT, bk, bv, Kp, Vp);

  for(int it = 0; it < ITERS_; ++it){
    qproj<<<512, 256, 0, stream>>>(slots, g_sl, b_sl, wq, bq, Qw);
    attn_part<<<dim3(512, NSPLIT_), 256, 0, stream>>>(Qw, Kp, Vp, Pml, Po);
    attn_merge<<<512, 256, 0, stream>>>(Pml, Po, Ow);
    float* outp = (it == ITERS_-1) ? (float*)d_out : slots;
    gru_mlp<<<128, 256, 0, stream>>>(Ow, slots, wo, bo, wihT, bih, whhT, bhh,
                                     w1, b1, w2, b2, g_ml, b_ml, outp);
  }
}

// Round 3
// 1238.478 us; speedup vs baseline: 1.0261x; 1.0261x over previous
//
#include <hip/hip_runtime.h>
#include <hip/hip_bf16.h>

#define B_ 64
#define N_ 4096
#define D_ 256
#define S_ 8
#define NH_ 8
#define DK_ 32
#define ITERS_ 3
#define MLPH_ 512
#define EPS_ 1e-5f
#define M_ (B_*N_)          // 262144 rows of x
#define NEG_BIG_ -3.0e38f   // finite sentinel: exp(NEG_BIG_-x) underflows to 0.f
#define NSPLIT_ 4           // attention N-partitions per (b,h)

typedef unsigned short u16;
typedef short bf16x8 __attribute__((ext_vector_type(8)));
typedef float f32x4 __attribute__((ext_vector_type(4)));

__device__ __forceinline__ u16 f2bf(float f){
  unsigned int x = __float_as_uint(f);
  return (u16)((x + 0x7fffu + ((x >> 16) & 1u)) >> 16);   // RNE
}
__device__ __forceinline__ unsigned int pkbf(float a, float b){
  return (unsigned int)f2bf(a) | ((unsigned int)f2bf(b) << 16);
}

// ---------------------------------------------------------------- prep
__global__ void prep_kernel(const float* __restrict__ wk, const float* __restrict__ wv,
                            const float* __restrict__ wih, const float* __restrict__ whh,
                            u16* __restrict__ wkvT, float* __restrict__ wihT,
                            float* __restrict__ whhT){
  int idx = blockIdx.x * 256 + threadIdx.x;
  if(idx < 512*256){
    int n = idx >> 8, k = idx & 255;
    float v = (n < 256) ? wk[k*256 + n] : wv[k*256 + (n-256)];
    wkvT[n*256 + k] = f2bf(v);
    return;
  }
  int i2 = idx - 512*256;
  if(i2 < 196608){           // w_ihT
    int d = i2 / 768, j = i2 - d*768;
    wihT[i2] = wih[j*256 + d];
    return;
  }
  int i3 = i2 - 196608;
  if(i3 < 196608){           // w_hhT
    int d = i3 / 768, j = i3 - d*768;
    whhT[i3] = whh[j*256 + d];
  }
}

// ---------------------------------------------------------------- slot init
__global__ void init_slots(const float* __restrict__ mu, const float* __restrict__ lsig,
                           const float* __restrict__ noise, float* __restrict__ slots){
  int idx = blockIdx.x * 256 + threadIdx.x;   // < 131072
  int d = idx & 255;
  slots[idx] = mu[d] + __expf(lsig[d]) * noise[idx];
}

// ---------------------------------------------------------------- LN(inputs) -> bf16
__global__ __launch_bounds__(256) void ln_kernel(const float* __restrict__ inp,
                                                 const float* __restrict__ g,
                                                 const float* __restrict__ b,
                                                 u16* __restrict__ xb){
  int wave = threadIdx.x >> 6, lane = threadIdx.x & 63;
  int row = blockIdx.x * 4 + wave;
  float4 v = *(const float4*)(inp + (size_t)row*D_ + lane*4);
  float s  = v.x+v.y+v.z+v.w;
  float ss = v.x*v.x + v.y*v.y + v.z*v.z + v.w*v.w;
  #pragma unroll
  for(int o=32;o>=1;o>>=1){ s += __shfl_xor(s,o,64); ss += __shfl_xor(ss,o,64); }
  float mean = s * (1.f/D_);
  float var  = ss * (1.f/D_) - mean*mean;
  float rstd = rsqrtf(var + EPS_);
  float4 gg = *(const float4*)(g + lane*4);
  float4 bb = *(const float4*)(b + lane*4);
  ushort4 o4;
  o4.x = f2bf((v.x-mean)*rstd*gg.x + bb.x);
  o4.y = f2bf((v.y-mean)*rstd*gg.y + bb.y);
  o4.z = f2bf((v.z-mean)*rstd*gg.z + bb.z);
  o4.w = f2bf((v.w-mean)*rstd*gg.w + bb.w);
  *(ushort4*)(xb + (size_t)row*D_ + lane*4) = o4;
}

// ---------------------------------------------------------------- K/V projection GEMM
// K stored row-major [bh][n][32]; V stored TRANSPOSED [bh][d][n] for MFMA attention.
// Staging via global_load_lds (16B, DMA direct-to-LDS): LDS dest is linear
// (wave base + lane*16); source chunk index is XOR-preswizzled per lane so the
// fragment ds_read_b128 at chunk (c ^ (row&7)) is bank-conflict-free.
//   LDS[r][c] = G[r][c ^ (r&7)]  =>  read LDS[R][k ^ (R&7)] == G[R][k]
__global__ __launch_bounds__(512) void kv_gemm(const u16* __restrict__ xb,
                                               const u16* __restrict__ wkvT,
                                               const float* __restrict__ bk,
                                               const float* __restrict__ bv,
                                               u16* __restrict__ Kp, u16* __restrict__ Vp){
  __shared__ u16 As[128*64];
  __shared__ u16 Bs[256*64];
  int rt = blockIdx.x, ct = blockIdx.y;
  int tid = threadIdx.x;
  int w = tid >> 6, lane = tid & 63;
  int wm = w >> 2, wn = w & 3;           // 2x4 waves of 64x64
  int lr = lane & 15, quad = lane >> 4;
  int lrow = lane >> 3, lchk = lane & 7;
  int schk = lchk ^ lrow;                // pre-swizzled source chunk
  f32x4 zf = {0.f,0.f,0.f,0.f};
  f32x4 acc[4][4];
  #pragma unroll
  for(int mt=0;mt<4;mt++)
    #pragma unroll
    for(int nt=0;nt<4;nt++) acc[mt][nt] = zf;

  const u16* agp = xb   + (size_t)(rt*128)*256;
  const u16* bgp = wkvT + (size_t)(ct*256)*256;

  for(int kk=0; kk<4; kk++){
    __syncthreads();                      // prev ds_reads done before overwrite
    #pragma unroll
    for(int i=0;i<2;i++){                 // A tile: 128x64 bf16, 16 KB
      int r = w*16 + i*8 + lrow;
      __builtin_amdgcn_global_load_lds(
        (const __attribute__((address_space(1))) void*)(agp + (size_t)r*256 + kk*64 + schk*8),
        (__attribute__((address_space(3))) void*)(As + (w*16 + i*8)*64),
        16, 0, 0);
    }
    #pragma unroll
    for(int i=0;i<4;i++){                 // B tile: 256x64 bf16, 32 KB
      int r = w*32 + i*8 + lrow;
      __builtin_amdgcn_global_load_lds(
        (const __attribute__((address_space(1))) void*)(bgp + (size_t)r*256 + kk*64 + schk*8),
        (__attribute__((address_space(3))) void*)(Bs + (w*32 + i*8)*64),
        16, 0, 0);
    }
    __syncthreads();                      // compiler drains vmcnt(0) here
    #pragma unroll
    for(int k32=0;k32<64;k32+=32){
      int cq = (k32 >> 3) + quad;         // logical 16B-chunk index 0..7
      int cs = (cq ^ (lr & 7)) << 3;      // swizzled elem offset within row
      bf16x8 a[4], b[4];
      #pragma unroll
      for(int mt=0;mt<4;mt++)
        a[mt] = *(const bf16x8*)(As + (wm*64 + mt*16 + lr)*64 + cs);
      #pragma unroll
      for(int nt=0;nt<4;nt++)
        b[nt] = *(const bf16x8*)(Bs + (wn*64 + nt*16 + lr)*64 + cs);
      #pragma unroll
      for(int mt=0;mt<4;mt++)
        #pragma unroll
        for(int nt=0;nt<4;nt++)
          acc[mt][nt] = __builtin_amdgcn_mfma_f32_16x16x32_bf16(a[mt], b[nt], acc[mt][nt], 0,0,0);
    }
  }
  // epilogue: C[row=quad*4+i][col=lr]
  #pragma unroll
  for(int mt=0;mt<4;mt++){
    #pragma unroll
    for(int nt=0;nt<4;nt++){
      int gc = ct*256 + wn*64 + nt*16 + lr;
      int gr0 = rt*128 + wm*64 + mt*16 + quad*4;
      #pragma unroll
      for(int i=0;i<4;i++){
        int gr = gr0 + i;
        int bb = gr >> 12, n = gr & 4095;
        float v = acc[mt][nt][i];
        if(gc < 256){
          int h = gc >> 5, d = gc & 31;
          Kp[((size_t)(bb*8 + h)*4096 + n)*32 + d] = f2bf(v + bk[gc]);
        } else {
          int c2 = gc - 256;
          int h = c2 >> 5, d = c2 & 31;
          // V^T layout: [bh][d][n]
          Vp[((size_t)(bb*8 + h)*32 + d)*4096 + n] = f2bf(v + bv[c2]);
        }
      }
    }
  }
}

// ---------------------------------------------------------------- LN(slots)+Q proj
__global__ __launch_bounds__(256) void qproj(const float* __restrict__ slots,
                                             const float* __restrict__ g,
                                             const float* __restrict__ b,
                                             const float* __restrict__ wq,
                                             const float* __restrict__ bq,
                                             float* __restrict__ Q){
  __shared__ float sp[256];
  __shared__ float red[8];
  int r = blockIdx.x, t = threadIdx.x;
  float v = slots[r*256 + t];
  float s1 = v, s2 = v*v;
  #pragma unroll
  for(int o=32;o>=1;o>>=1){ s1 += __shfl_xor(s1,o,64); s2 += __shfl_xor(s2,o,64); }
  int wv_ = t >> 6, lane = t & 63;
  if(lane==0){ red[wv_] = s1; red[4+wv_] = s2; }
  __syncthreads();
  float fs1 = red[0]+red[1]+red[2]+red[3];
  float fs2 = red[4]+red[5]+red[6]+red[7];
  float mean = fs1*(1.f/256.f);
  float var  = fs2*(1.f/256.f) - mean*mean;
  float rstd = rsqrtf(var + EPS_);
  sp[t] = (v - mean)*rstd*g[t] + b[t];
  __syncthreads();
  float acc = bq[t];
  for(int d=0; d<256; d++) acc = fmaf(sp[d], wq[d*256 + t], acc);
  int b_ = r >> 3, s_ = r & 7;
  int h = t >> 5, d_ = t & 31;
  Q[((b_*8 + h)*8 + s_)*32 + d_] = acc;
}

// ---------------------------------------------------------------- attention (MFMA, slot-shared)
// grid (512, NSPLIT_); block = 256 (4 waves). Block = (b,h); each wave owns a
// 256-row slice of its 1024-row split and computes ALL 8 slots via MFMA:
//   scores^T: C1[n16][s] = mfma(A=K rows [n x d], B=Q^T [d x s])
//   out^T   : C2[d16][s] = mfma(A=V^T rows [d x n], B=P [n x s])
// Softmax state lives at s = lane&15 in both C1 and C2 layouts -> no cross-lane
// moves for m/l/corr. P is repacked C1->B via 4 packs + 8 shuffles + 4 selects.
// 4 wave-partials merged in LDS -> same Pml/Po format as before (NSPLIT_ parts).
__global__ __launch_bounds__(256) void attn_part(const float* __restrict__ Qw,
                                                 const u16* __restrict__ Kp,
                                                 const u16* __restrict__ Vp,
                                                 float2* __restrict__ Pml,
                                                 float* __restrict__ Po){
  const int bh = blockIdx.x, sp_ = blockIdx.y;
  const int w = threadIdx.x >> 6, lane = threadIdx.x & 63;
  const int c = lane & 15, q = lane >> 4;
  const float scale = 0.17677669529663687f;   // 1/sqrt(32)

  __shared__ float oW[4][8][32];
  __shared__ float mW[4][8], lW[4][8];

  // B1 fragment: Q^T, lane holds Q[s=c][d=8q+e]; zeros for padded slots c>=8
  bf16x8 qf;
  {
    union { u16 u[8]; bf16x8 v; } qq;
    if(c < 8){
      const float4* qp = (const float4*)(Qw + ((size_t)bh*8 + c)*32 + q*8);
      float4 v0 = qp[0], v1 = qp[1];
      qq.u[0]=f2bf(v0.x); qq.u[1]=f2bf(v0.y); qq.u[2]=f2bf(v0.z); qq.u[3]=f2bf(v0.w);
      qq.u[4]=f2bf(v1.x); qq.u[5]=f2bf(v1.y); qq.u[6]=f2bf(v1.z); qq.u[7]=f2bf(v1.w);
    } else {
      #pragma unroll
      for(int e=0;e<8;e++) qq.u[e]=0;
    }
    qf = qq.v;
  }

  const int row0 = sp_*(N_/NSPLIT_) + w*(N_/NSPLIT_/4);     // 256-row sub-slice
  const u16* kb = Kp + (size_t)bh*(N_*DK_) + (size_t)row0*DK_;  // K[n][d]
  const u16* vt = Vp + (size_t)bh*(N_*DK_) + row0;              // V^T[d][n]

  float m = NEG_BIG_, l = 0.f;
  f32x4 acc2[2] = {{0.f,0.f,0.f,0.f},{0.f,0.f,0.f,0.f}};
  const int La = c + 32*(q&1);     // shuffle source lanes for P repack
  const int Lb = La + 16;
  const int thi = q >> 1;

  #pragma unroll 2
  for(int ch=0; ch<8; ch++){                 // 8 chunks of 32 rows
    // A1 fragments: K[row0+ch*32+16t+c][8q..8q+7]  (b128 each)
    bf16x8 kf0 = *(const bf16x8*)(kb + (size_t)(ch*32 +      c)*DK_ + q*8);
    bf16x8 kf1 = *(const bf16x8*)(kb + (size_t)(ch*32 + 16 + c)*DK_ + q*8);
    // A2 fragments: V^T[16t+c][row0+ch*32+8q .. +7]  (b128 each)
    bf16x8 vf0 = *(const bf16x8*)(vt + (size_t)(     c)*N_ + ch*32 + q*8);
    bf16x8 vf1 = *(const bf16x8*)(vt + (size_t)(16 + c)*N_ + ch*32 + q*8);

    f32x4 s0 = {0.f,0.f,0.f,0.f}, s1 = {0.f,0.f,0.f,0.f};
    s0 = __builtin_amdgcn_mfma_f32_16x16x32_bf16(kf0, qf, s0, 0,0,0);
    s1 = __builtin_amdgcn_mfma_f32_16x16x32_bf16(kf1, qf, s1, 0,0,0);

    // lane holds scores for s=c at n = ch*32 + 16t + 4q + r
    float p[8];
    #pragma unroll
    for(int r=0;r<4;r++){ p[r] = s0[r]*scale; p[4+r] = s1[r]*scale; }
    float cm = p[0];
    #pragma unroll
    for(int i=1;i<8;i++) cm = fmaxf(cm, p[i]);
    cm = fmaxf(cm, __shfl_xor(cm, 16, 64));
    cm = fmaxf(cm, __shfl_xor(cm, 32, 64));
    float nm = fmaxf(m, cm);
    float corr = __expf(m - nm);
    m = nm;
    float ps = 0.f;
    #pragma unroll
    for(int i=0;i<8;i++){ p[i] = __expf(p[i] - nm); ps += p[i]; }
    ps += __shfl_xor(ps, 16, 64);
    ps += __shfl_xor(ps, 32, 64);
    l = l*corr + ps;
    #pragma unroll
    for(int r=0;r<4;r++){ acc2[0][r] *= corr; acc2[1][r] *= corr; }

    // repack P (C1 layout) -> B2 fragment: lane needs P[n=8q+e][s=c]
    unsigned int u0 = pkbf(p[0],p[1]), u1 = pkbf(p[2],p[3]);
    unsigned int u2 = pkbf(p[4],p[5]), u3 = pkbf(p[6],p[7]);
    unsigned int a0 = (unsigned int)__shfl((int)u0, La, 64);
    unsigned int a1 = (unsigned int)__shfl((int)u1, La, 64);
    unsigned int a2 = (unsigned int)__shfl((int)u2, La, 64);
    unsigned int a3 = (unsigned int)__shfl((int)u3, La, 64);
    unsigned int b0 = (unsigned int)__shfl((int)u0, Lb, 64);
    unsigned int b1 = (unsigned int)__shfl((int)u1, Lb, 64);
    unsigned int b2 = (unsigned int)__shfl((int)u2, Lb, 64);
    unsigned int b3 = (unsigned int)__shfl((int)u3, Lb, 64);
    union { unsigned int wu[4]; bf16x8 v; } pf;
    pf.wu[0] = thi ? a2 : a0;
    pf.wu[1] = thi ? a3 : a1;
    pf.wu[2] = thi ? b2 : b0;
    pf.wu[3] = thi ? b3 : b1;

    acc2[0] = __builtin_amdgcn_mfma_f32_16x16x32_bf16(vf0, pf.v, acc2[0], 0,0,0);
    acc2[1] = __builtin_amdgcn_mfma_f32_16x16x32_bf16(vf1, pf.v, acc2[1], 0,0,0);
  }

  // wave partials -> LDS.  acc2[t][r] = out^T[d=16t+4q+r][s=c] (unnormalized)
  if(c < 8){
    #pragma unroll
    for(int t=0;t<2;t++)
      #pragma unroll
      for(int r=0;r<4;r++)
        oW[w][c][16*t + 4*q + r] = acc2[t][r];
    if(q == 0){ mW[w][c] = m; lW[w][c] = l; }
  }
  __syncthreads();
  {
    int s = threadIdx.x >> 5, d = threadIdx.x & 31;   // 8 x 32 = 256 threads
    float M = fmaxf(fmaxf(mW[0][s], mW[1][s]), fmaxf(mW[2][s], mW[3][s]));
    float L = 0.f, O = 0.f;
    #pragma unroll
    for(int k=0;k<4;k++){
      float e = __expf(mW[k][s] - M);
      L += lW[k][s]*e;
      O += oW[k][s][d]*e;
    }
    Po[((size_t)(bh*8 + s)*NSPLIT_ + sp_)*32 + d] = O;   // unnormalized
    if(d == 0) Pml[(bh*8 + s)*NSPLIT_ + sp_] = make_float2(M, L);
  }
}

// ---------------------------------------------------------------- merge split partials -> Ow
// one thread per (row, d): row = (bh*8+s) in [0,4096), d in [0,32)
__global__ __launch_bounds__(256) void attn_merge(const float2* __restrict__ Pml,
                                                  const float* __restrict__ Po,
                                                  float* __restrict__ Ow){
  int gid = blockIdx.x * 256 + threadIdx.x;   // < 131072
  int row = gid >> 5, d = gid & 31;
  float2 ml[NSPLIT_];
  #pragma unroll
  for(int k=0;k<NSPLIT_;k++) ml[k] = Pml[row*NSPLIT_ + k];
  float M = ml[0].x;
  #pragma unroll
  for(int k=1;k<NSPLIT_;k++) M = fmaxf(M, ml[k].x);
  float L = 0.f, o = 0.f;
  #pragma unroll
  for(int k=0;k<NSPLIT_;k++){
    float e = __expf(ml[k].x - M);
    L += ml[k].y * e;
    o += Po[(size_t)(row*NSPLIT_ + k)*32 + d] * e;
  }
  Ow[row*32 + d] = o / L;
}

// ---------------------------------------------------------------- out-proj + GRU + LN + MLP
__global__ __launch_bounds__(256) void gru_mlp(const float* __restrict__ Ain,
    const float* __restrict__ slots_in,
    const float* __restrict__ wo,  const float* __restrict__ bo,
    const float* __restrict__ wihT,const float* __restrict__ bih,
    const float* __restrict__ whhT,const float* __restrict__ bhh,
    const float* __restrict__ w1,  const float* __restrict__ b1,
    const float* __restrict__ w2,  const float* __restrict__ b2,
    const float* __restrict__ gm,  const float* __restrict__ bm,
    float* __restrict__ slots_out){
  __shared__ float xr[4][256], hr[4][256], o2[4][256], hnew[4][256], hid[4][512];
  __shared__ float red[4][8];
  int t = threadIdx.x, r0 = blockIdx.x*4;
  int wv_ = t >> 6, lane = t & 63;
  #pragma unroll
  for(int rr=0;rr<4;rr++){
    int r = r0+rr, b_ = r>>3, s_ = r&7;
    int h = t>>5, d = t&31;
    xr[rr][t] = Ain[((b_*8 + h)*8 + s_)*32 + d];   // un-transpose heads
    hr[rr][t] = slots_in[r*256 + t];
  }
  __syncthreads();
  { // out2 = xr @ wo + bo
    float a0=0,a1=0,a2=0,a3=0;
    for(int d=0; d<256; d++){
      float w = wo[d*256 + t];
      a0 = fmaf(xr[0][d],w,a0); a1 = fmaf(xr[1][d],w,a1);
      a2 = fmaf(xr[2][d],w,a2); a3 = fmaf(xr[3][d],w,a3);
    }
    float bv = bo[t];
    o2[0][t]=a0+bv; o2[1][t]=a1+bv; o2[2][t]=a2+bv; o2[3][t]=a3+bv;
  }
  __syncthreads();
  { // GRU gates
    float ir[4]={}, iz[4]={}, inn[4]={}, hrr[4]={}, hz[4]={}, hn[4]={};
    for(int d=0; d<256; d++){
      float wi0 = wihT[d*768 + t], wi1 = wihT[d*768 + 256 + t], wi2 = wihT[d*768 + 512 + t];
      float wh0 = whhT[d*768 + t], wh1 = whhT[d*768 + 256 + t], wh2 = whhT[d*768 + 512 + t];
      #pragma unroll
      for(int rr=0;rr<4;rr++){
        float xo = o2[rr][d], hh = hr[rr][d];
        ir[rr]  = fmaf(xo,wi0,ir[rr]);  iz[rr] = fmaf(xo,wi1,iz[rr]);  inn[rr] = fmaf(xo,wi2,inn[rr]);
        hrr[rr] = fmaf(hh,wh0,hrr[rr]); hz[rr] = fmaf(hh,wh1,hz[rr]);  hn[rr]  = fmaf(hh,wh2,hn[rr]);
      }
    }
    float bi0 = bih[t], bi1 = bih[256+t], bi2 = bih[512+t];
    float bh0 = bhh[t], bh1 = bhh[256+t], bh2 = bhh[512+t];
    #pragma unroll
    for(int rr=0;rr<4;rr++){
      float rg = 1.f/(1.f + __expf(-(ir[rr]+bi0 + hrr[rr]+bh0)));
      float zg = 1.f/(1.f + __expf(-(iz[rr]+bi1 + hz[rr]+bh1)));
      float ng = tanhf(inn[rr]+bi2 + rg*(hn[rr]+bh2));
      hnew[rr][t] = (1.f - zg)*ng + zg*hr[rr][t];
    }
  }
  __syncthreads();
  // LN(hnew) per row -> m stored in xr (xr is dead)
  #pragma unroll
  for(int rr=0;rr<4;rr++){
    float v = hnew[rr][t];
    float s1=v, s2=v*v;
    #pragma unroll
    for(int o=32;o>=1;o>>=1){ s1 += __shfl_xor(s1,o,64); s2 += __shfl_xor(s2,o,64); }
    if(lane==0){ red[rr][wv_]=s1; red[rr][4+wv_]=s2; }
  }
  __syncthreads();
  {
    float gmt = gm[t], bmt = bm[t];
    #pragma unroll
    for(int rr=0;rr<4;rr++){
      float fs1 = red[rr][0]+red[rr][1]+red[rr][2]+red[rr][3];
      float fs2 = red[rr][4]+red[rr][5]+red[rr][6]+red[rr][7];
      float mean = fs1*(1.f/256.f);
      float var  = fs2*(1.f/256.f) - mean*mean;
      float rstd = rsqrtf(var + EPS_);
      xr[rr][t] = (hnew[rr][t]-mean)*rstd*gmt + bmt;
    }
  }
  __syncthreads();
  { // hid = relu(m @ w1 + b1)
    float c0[4]={}, c1[4]={};
    for(int d=0; d<256; d++){
      float wA = w1[d*512 + t], wB = w1[d*512 + 256 + t];
      #pragma unroll
      for(int rr=0;rr<4;rr++){ float mv = xr[rr][d]; c0[rr]=fmaf(mv,wA,c0[rr]); c1[rr]=fmaf(mv,wB,c1[rr]); }
    }
    float b1a = b1[t], b1b = b1[256+t];
    #pragma unroll
    for(int rr=0;rr<4;rr++){
      hid[rr][t]     = fmaxf(c0[rr]+b1a, 0.f);
      hid[rr][t+256] = fmaxf(c1[rr]+b1b, 0.f);
    }
  }
  __syncthreads();
  { // slots_out = hnew + hid @ w2 + b2
    float a[4]={};
    for(int k=0;k<512;k++){
      float w = w2[k*256 + t];
      #pragma unroll
      for(int rr=0;rr<4;rr++) a[rr] = fmaf(hid[rr][k], w, a[rr]);
    }
    float b2t = b2[t];
    #pragma unroll
    for(int rr=0;rr<4;rr++){
      int r = r0+rr;
      slots_out[r*256 + t] = hnew[rr][t] + a[rr] + b2t;
    }
  }
}

// ----------------------------------------------------------------
extern "C" void kernel_launch(void* const* d_in, const int* in_sizes, int n_in,
                              void* d_out, int out_size, void* d_ws, size_t ws_size,
                              hipStream_t stream){
  const float* inputs = (const float*)d_in[0];
  const float* noise  = (const float*)d_in[1];
  const float* mu     = (const float*)d_in[2];
  const float* lsig   = (const float*)d_in[3];
  const float* wq  = (const float*)d_in[4];  const float* bq  = (const float*)d_in[5];
  const float* wk  = (const float*)d_in[6];  const float* bk  = (const float*)d_in[7];
  const float* wv  = (const float*)d_in[8];  const float* bv  = (const float*)d_in[9];
  const float* wo  = (const float*)d_in[10]; const float* bo  = (const float*)d_in[11];
  const float* wih = (const float*)d_in[12]; const float* bih = (const float*)d_in[13];
  const float* whh = (const float*)d_in[14]; const float* bhh = (const float*)d_in[15];
  const float* w1  = (const float*)d_in[16]; const float* b1  = (const float*)d_in[17];
  const float* w2  = (const float*)d_in[18]; const float* b2  = (const float*)d_in[19];
  const float* g_in= (const float*)d_in[20]; const float* b_in= (const float*)d_in[21];
  const float* g_sl= (const float*)d_in[22]; const float* b_sl= (const float*)d_in[23];
  const float* g_ml= (const float*)d_in[24]; const float* b_ml= (const float*)d_in[25];

  const size_t sz_big = (size_t)M_ * D_ * 2;   // 134,217,728 B each
  size_t need = 3*sz_big + 512*256*2 + 2*(256*768*4) + 3*(512*256*4)
              + 4096*NSPLIT_*8 + (size_t)4096*NSPLIT_*32*4;
  if(ws_size < need) return;

  char* p = (char*)d_ws;
  u16*   xb   = (u16*)p;   p += sz_big;
  u16*   Kp   = (u16*)p;   p += sz_big;
  u16*   Vp   = (u16*)p;   p += sz_big;      // holds V^T [bh][d][n]
  u16*   wkvT = (u16*)p;   p += 512*256*2;
  float* wihT = (float*)p; p += 256*768*4;
  float* whhT = (float*)p; p += 256*768*4;
  float* slots= (float*)p; p += 512*256*4;
  float* Qw   = (float*)p; p += 512*256*4;
  float* Ow   = (float*)p; p += 512*256*4;
  float2* Pml = (float2*)p; p += 4096*NSPLIT_*8;
  float* Po   = (float*)p;  p += (size_t)4096*NSPLIT_*32*4;

  prep_kernel<<<2048, 256, 0, stream>>>(wk, wv, wih, whh, wkvT, wihT, whhT);
  init_slots <<<512, 256, 0, stream>>>(mu, lsig, noise, slots);
  ln_kernel  <<<M_/4, 256, 0, stream>>>(inputs, g_in, b_in, xb);
  kv_gemm    <<<dim3(M_/128, 2), 512, 0, stream>>>(xb, wkvT, bk, bv, Kp, Vp);

  for(int it = 0; it < ITERS_; ++it){
    qproj<<<512, 256, 0, stream>>>(slots, g_sl, b_sl, wq, bq, Qw);
    attn_part<<<dim3(512, NSPLIT_), 256, 0, stream>>>(Qw, Kp, Vp, Pml, Po);
    attn_merge<<<512, 256, 0, stream>>>(Pml, Po, Ow);
    float* outp = (it == ITERS_-1) ? (float*)d_out : slots;
    gru_mlp<<<128, 256, 0, stream>>>(Ow, slots, wo, bo, wihT, bih, whhT, bhh,
                                     w1, b1, w2, b2, g_ml, b_ml, outp);
  }
}

// Round 4
// 1193.419 us; speedup vs baseline: 1.0648x; 1.0378x over previous
//
#include <hip/hip_runtime.h>
#include <hip/hip_bf16.h>

#define B_ 64
#define N_ 4096
#define D_ 256
#define S_ 8
#define NH_ 8
#define DK_ 32
#define ITERS_ 3
#define MLPH_ 512
#define EPS_ 1e-5f
#define M_ (B_*N_)          // 262144 rows of x
#define NEG_BIG_ -3.0e38f   // finite sentinel: exp(NEG_BIG_-x) underflows to 0.f
#define NSPLIT_ 4           // attention N-partitions per (b,h)

typedef unsigned short u16;
typedef short bf16x8 __attribute__((ext_vector_type(8)));
typedef float f32x4 __attribute__((ext_vector_type(4)));

__device__ __forceinline__ u16 f2bf(float f){
  unsigned int x = __float_as_uint(f);
  return (u16)((x + 0x7fffu + ((x >> 16) & 1u)) >> 16);   // RNE
}
__device__ __forceinline__ unsigned int pkbf(float a, float b){
  return (unsigned int)f2bf(a) | ((unsigned int)f2bf(b) << 16);
}

// ---------------------------------------------------------------- prep
__global__ void prep_kernel(const float* __restrict__ wk, const float* __restrict__ wv,
                            const float* __restrict__ wih, const float* __restrict__ whh,
                            u16* __restrict__ wkvT, float* __restrict__ wihT,
                            float* __restrict__ whhT){
  int idx = blockIdx.x * 256 + threadIdx.x;
  if(idx < 512*256){
    int n = idx >> 8, k = idx & 255;
    float v = (n < 256) ? wk[k*256 + n] : wv[k*256 + (n-256)];
    wkvT[n*256 + k] = f2bf(v);
    return;
  }
  int i2 = idx - 512*256;
  if(i2 < 196608){           // w_ihT
    int d = i2 / 768, j = i2 - d*768;
    wihT[i2] = wih[j*256 + d];
    return;
  }
  int i3 = i2 - 196608;
  if(i3 < 196608){           // w_hhT
    int d = i3 / 768, j = i3 - d*768;
    whhT[i3] = whh[j*256 + d];
  }
}

// ---------------------------------------------------------------- slot init
__global__ void init_slots(const float* __restrict__ mu, const float* __restrict__ lsig,
                           const float* __restrict__ noise, float* __restrict__ slots){
  int idx = blockIdx.x * 256 + threadIdx.x;   // < 131072
  int d = idx & 255;
  slots[idx] = mu[d] + __expf(lsig[d]) * noise[idx];
}

// ---------------------------------------------------------------- LN(inputs) -> bf16
__global__ __launch_bounds__(256) void ln_kernel(const float* __restrict__ inp,
                                                 const float* __restrict__ g,
                                                 const float* __restrict__ b,
                                                 u16* __restrict__ xb){
  int wave = threadIdx.x >> 6, lane = threadIdx.x & 63;
  int row = blockIdx.x * 4 + wave;
  float4 v = *(const float4*)(inp + (size_t)row*D_ + lane*4);
  float s  = v.x+v.y+v.z+v.w;
  float ss = v.x*v.x + v.y*v.y + v.z*v.z + v.w*v.w;
  #pragma unroll
  for(int o=32;o>=1;o>>=1){ s += __shfl_xor(s,o,64); ss += __shfl_xor(ss,o,64); }
  float mean = s * (1.f/D_);
  float var  = ss * (1.f/D_) - mean*mean;
  float rstd = rsqrtf(var + EPS_);
  float4 gg = *(const float4*)(g + lane*4);
  float4 bb = *(const float4*)(b + lane*4);
  ushort4 o4;
  o4.x = f2bf((v.x-mean)*rstd*gg.x + bb.x);
  o4.y = f2bf((v.y-mean)*rstd*gg.y + bb.y);
  o4.z = f2bf((v.z-mean)*rstd*gg.z + bb.z);
  o4.w = f2bf((v.w-mean)*rstd*gg.w + bb.w);
  *(ushort4*)(xb + (size_t)row*D_ + lane*4) = o4;
}

// ---------------------------------------------------------------- K/V projection GEMM
// K stored row-major [bh][n][32]; V stored TRANSPOSED [bh][d][n].
// Single-barrier structure: A tile (64 rows x 256 k, 32 KB) staged ONCE via
// global_load_lds with XOR swizzle (LDS[r][c16] = G[r][c16^(r&7)], 16B chunks);
// B (wkvT, 256 KB, L2-hot) is read directly from global inside the barrier-free
// MFMA loop so the compiler pipelines B-loads under MFMA with counted vmcnt.
// Block = 8 waves, each 64 rows x 64 cols -> all 512 output cols, A read once.
__global__ __launch_bounds__(512) void kv_gemm(const u16* __restrict__ xb,
                                               const u16* __restrict__ wkvT,
                                               const float* __restrict__ bk,
                                               const float* __restrict__ bv,
                                               u16* __restrict__ Kp, u16* __restrict__ Vp){
  __shared__ u16 As[64*256];                  // 32 KB
  int rt = blockIdx.x;                        // 0..4095, 64-row strip
  int tid = threadIdx.x;
  int w = tid >> 6, lane = tid & 63;
  int lr = lane & 15, quad = lane >> 4;

  // ---- stage A tile: each wave issues 4 x 1KB DMA (2 rows each)
  {
    const u16* agp = xb + (size_t)(rt*64)*256;
    int i0 = w*4;
    #pragma unroll
    for(int i=0;i<4;i++){
      int r = 2*(i0+i) + (lane >> 5);
      int c16 = lane & 31;
      __builtin_amdgcn_global_load_lds(
        (const __attribute__((address_space(1))) void*)(agp + (size_t)r*256 + ((c16 ^ (r&7)) << 3)),
        (__attribute__((address_space(3))) void*)(As + (i0+i)*512),
        16, 0, 0);
    }
  }

  f32x4 zf = {0.f,0.f,0.f,0.f};
  f32x4 acc[4][4];
  #pragma unroll
  for(int mt=0;mt<4;mt++)
    #pragma unroll
    for(int nt=0;nt<4;nt++) acc[mt][nt] = zf;

  const u16* bw = wkvT + (size_t)(w*64)*256;  // this wave's 64-col strip of B

  __syncthreads();                            // A tile ready (vmcnt drained here)

  // ---- barrier-free MFMA loop: 8 k-chunks of 32
  #pragma unroll 2
  for(int kc=0; kc<8; kc++){
    bf16x8 a[4], b[4];
    #pragma unroll
    for(int mt=0;mt<4;mt++){
      int R = mt*16 + lr;
      int chunk = kc*4 + quad;
      int sw = (chunk & 0x18) | ((chunk ^ R) & 7);
      a[mt] = *(const bf16x8*)(As + R*256 + sw*8);
    }
    #pragma unroll
    for(int nt=0;nt<4;nt++)
      b[nt] = *(const bf16x8*)(bw + (size_t)(nt*16 + lr)*256 + kc*32 + quad*8);
    #pragma unroll
    for(int mt=0;mt<4;mt++)
      #pragma unroll
      for(int nt=0;nt<4;nt++)
        acc[mt][nt] = __builtin_amdgcn_mfma_f32_16x16x32_bf16(a[mt], b[nt], acc[mt][nt], 0,0,0);
  }

  // ---- epilogue: C[row=quad*4+i][col=lr]
  #pragma unroll
  for(int mt=0;mt<4;mt++){
    #pragma unroll
    for(int nt=0;nt<4;nt++){
      int gc = w*64 + nt*16 + lr;             // 0..511
      int gr0 = rt*64 + mt*16 + quad*4;
      #pragma unroll
      for(int i=0;i<4;i++){
        int gr = gr0 + i;
        int bb = gr >> 12, n = gr & 4095;
        float v = acc[mt][nt][i];
        if(gc < 256){
          int h = gc >> 5, d = gc & 31;
          Kp[((size_t)(bb*8 + h)*4096 + n)*32 + d] = f2bf(v + bk[gc]);
        } else {
          int c2 = gc - 256;
          int h = c2 >> 5, d = c2 & 31;
          // V^T layout: [bh][d][n]
          Vp[((size_t)(bb*8 + h)*32 + d)*4096 + n] = f2bf(v + bv[c2]);
        }
      }
    }
  }
}

// ---------------------------------------------------------------- LN(slots)+Q proj
__global__ __launch_bounds__(256) void qproj(const float* __restrict__ slots,
                                             const float* __restrict__ g,
                                             const float* __restrict__ b,
                                             const float* __restrict__ wq,
                                             const float* __restrict__ bq,
                                             float* __restrict__ Q){
  __shared__ float sp[256];
  __shared__ float red[8];
  int r = blockIdx.x, t = threadIdx.x;
  float v = slots[r*256 + t];
  float s1 = v, s2 = v*v;
  #pragma unroll
  for(int o=32;o>=1;o>>=1){ s1 += __shfl_xor(s1,o,64); s2 += __shfl_xor(s2,o,64); }
  int wv_ = t >> 6, lane = t & 63;
  if(lane==0){ red[wv_] = s1; red[4+wv_] = s2; }
  __syncthreads();
  float fs1 = red[0]+red[1]+red[2]+red[3];
  float fs2 = red[4]+red[5]+red[6]+red[7];
  float mean = fs1*(1.f/256.f);
  float var  = fs2*(1.f/256.f) - mean*mean;
  float rstd = rsqrtf(var + EPS_);
  sp[t] = (v - mean)*rstd*g[t] + b[t];
  __syncthreads();
  float acc = bq[t];
  for(int d=0; d<256; d++) acc = fmaf(sp[d], wq[d*256 + t], acc);
  int b_ = r >> 3, s_ = r & 7;
  int h = t >> 5, d_ = t & 31;
  Q[((b_*8 + h)*8 + s_)*32 + d_] = acc;
}

// ---------------------------------------------------------------- attention (MFMA, slot-shared)
// grid (512, NSPLIT_); block = 256 (4 waves). Block = (b,h); each wave owns a
// 256-row slice of its 1024-row split and computes ALL 8 slots via MFMA:
//   scores^T: C1[n16][s] = mfma(A=K rows [n x d], B=Q^T [d x s])
//   out^T   : C2[d16][s] = mfma(A=V^T rows [d x n], B=P [n x s])
// Softmax state lives at s = lane&15 in both C1 and C2 layouts -> no cross-lane
// moves for m/l/corr. P is repacked C1->B via 4 packs + 8 shuffles + 4 selects.
// 4 wave-partials merged in LDS -> same Pml/Po format as before (NSPLIT_ parts).
__global__ __launch_bounds__(256) void attn_part(const float* __restrict__ Qw,
                                                 const u16* __restrict__ Kp,
                                                 const u16* __restrict__ Vp,
                                                 float2* __restrict__ Pml,
                                                 float* __restrict__ Po){
  const int bh = blockIdx.x, sp_ = blockIdx.y;
  const int w = threadIdx.x >> 6, lane = threadIdx.x & 63;
  const int c = lane & 15, q = lane >> 4;
  const float scale = 0.17677669529663687f;   // 1/sqrt(32)

  __shared__ float oW[4][8][32];
  __shared__ float mW[4][8], lW[4][8];

  // B1 fragment: Q^T, lane holds Q[s=c][d=8q+e]; zeros for padded slots c>=8
  bf16x8 qf;
  {
    union { u16 u[8]; bf16x8 v; } qq;
    if(c < 8){
      const float4* qp = (const float4*)(Qw + ((size_t)bh*8 + c)*32 + q*8);
      float4 v0 = qp[0], v1 = qp[1];
      qq.u[0]=f2bf(v0.x); qq.u[1]=f2bf(v0.y); qq.u[2]=f2bf(v0.z); qq.u[3]=f2bf(v0.w);
      qq.u[4]=f2bf(v1.x); qq.u[5]=f2bf(v1.y); qq.u[6]=f2bf(v1.z); qq.u[7]=f2bf(v1.w);
    } else {
      #pragma unroll
      for(int e=0;e<8;e++) qq.u[e]=0;
    }
    qf = qq.v;
  }

  const int row0 = sp_*(N_/NSPLIT_) + w*(N_/NSPLIT_/4);     // 256-row sub-slice
  const u16* kb = Kp + (size_t)bh*(N_*DK_) + (size_t)row0*DK_;  // K[n][d]
  const u16* vt = Vp + (size_t)bh*(N_*DK_) + row0;              // V^T[d][n]

  float m = NEG_BIG_, l = 0.f;
  f32x4 acc2[2] = {{0.f,0.f,0.f,0.f},{0.f,0.f,0.f,0.f}};
  const int La = c + 32*(q&1);     // shuffle source lanes for P repack
  const int Lb = La + 16;
  const int thi = q >> 1;

  #pragma unroll 2
  for(int ch=0; ch<8; ch++){                 // 8 chunks of 32 rows
    // A1 fragments: K[row0+ch*32+16t+c][8q..8q+7]  (b128 each)
    bf16x8 kf0 = *(const bf16x8*)(kb + (size_t)(ch*32 +      c)*DK_ + q*8);
    bf16x8 kf1 = *(const bf16x8*)(kb + (size_t)(ch*32 + 16 + c)*DK_ + q*8);
    // A2 fragments: V^T[16t+c][row0+ch*32+8q .. +7]  (b128 each)
    bf16x8 vf0 = *(const bf16x8*)(vt + (size_t)(     c)*N_ + ch*32 + q*8);
    bf16x8 vf1 = *(const bf16x8*)(vt + (size_t)(16 + c)*N_ + ch*32 + q*8);

    f32x4 s0 = {0.f,0.f,0.f,0.f}, s1 = {0.f,0.f,0.f,0.f};
    s0 = __builtin_amdgcn_mfma_f32_16x16x32_bf16(kf0, qf, s0, 0,0,0);
    s1 = __builtin_amdgcn_mfma_f32_16x16x32_bf16(kf1, qf, s1, 0,0,0);

    // lane holds scores for s=c at n = ch*32 + 16t + 4q + r
    float p[8];
    #pragma unroll
    for(int r=0;r<4;r++){ p[r] = s0[r]*scale; p[4+r] = s1[r]*scale; }
    float cm = p[0];
    #pragma unroll
    for(int i=1;i<8;i++) cm = fmaxf(cm, p[i]);
    cm = fmaxf(cm, __shfl_xor(cm, 16, 64));
    cm = fmaxf(cm, __shfl_xor(cm, 32, 64));
    float nm = fmaxf(m, cm);
    float corr = __expf(m - nm);
    m = nm;
    float ps = 0.f;
    #pragma unroll
    for(int i=0;i<8;i++){ p[i] = __expf(p[i] - nm); ps += p[i]; }
    ps += __shfl_xor(ps, 16, 64);
    ps += __shfl_xor(ps, 32, 64);
    l = l*corr + ps;
    #pragma unroll
    for(int r=0;r<4;r++){ acc2[0][r] *= corr; acc2[1][r] *= corr; }

    // repack P (C1 layout) -> B2 fragment: lane needs P[n=8q+e][s=c]
    unsigned int u0 = pkbf(p[0],p[1]), u1 = pkbf(p[2],p[3]);
    unsigned int u2 = pkbf(p[4],p[5]), u3 = pkbf(p[6],p[7]);
    unsigned int a0 = (unsigned int)__shfl((int)u0, La, 64);
    unsigned int a1 = (unsigned int)__shfl((int)u1, La, 64);
    unsigned int a2 = (unsigned int)__shfl((int)u2, La, 64);
    unsigned int a3 = (unsigned int)__shfl((int)u3, La, 64);
    unsigned int b0 = (unsigned int)__shfl((int)u0, Lb, 64);
    unsigned int b1 = (unsigned int)__shfl((int)u1, Lb, 64);
    unsigned int b2 = (unsigned int)__shfl((int)u2, Lb, 64);
    unsigned int b3 = (unsigned int)__shfl((int)u3, Lb, 64);
    union { unsigned int wu[4]; bf16x8 v; } pf;
    pf.wu[0] = thi ? a2 : a0;
    pf.wu[1] = thi ? a3 : a1;
    pf.wu[2] = thi ? b2 : b0;
    pf.wu[3] = thi ? b3 : b1;

    acc2[0] = __builtin_amdgcn_mfma_f32_16x16x32_bf16(vf0, pf.v, acc2[0], 0,0,0);
    acc2[1] = __builtin_amdgcn_mfma_f32_16x16x32_bf16(vf1, pf.v, acc2[1], 0,0,0);
  }

  // wave partials -> LDS.  acc2[t][r] = out^T[d=16t+4q+r][s=c] (unnormalized)
  if(c < 8){
    #pragma unroll
    for(int t=0;t<2;t++)
      #pragma unroll
      for(int r=0;r<4;r++)
        oW[w][c][16*t + 4*q + r] = acc2[t][r];
    if(q == 0){ mW[w][c] = m; lW[w][c] = l; }
  }
  __syncthreads();
  {
    int s = threadIdx.x >> 5, d = threadIdx.x & 31;   // 8 x 32 = 256 threads
    float M = fmaxf(fmaxf(mW[0][s], mW[1][s]), fmaxf(mW[2][s], mW[3][s]));
    float L = 0.f, O = 0.f;
    #pragma unroll
    for(int k=0;k<4;k++){
      float e = __expf(mW[k][s] - M);
      L += lW[k][s]*e;
      O += oW[k][s][d]*e;
    }
    Po[((size_t)(bh*8 + s)*NSPLIT_ + sp_)*32 + d] = O;   // unnormalized
    if(d == 0) Pml[(bh*8 + s)*NSPLIT_ + sp_] = make_float2(M, L);
  }
}

// ---------------------------------------------------------------- merge split partials -> Ow
// one thread per (row, d): row = (bh*8+s) in [0,4096), d in [0,32)
__global__ __launch_bounds__(256) void attn_merge(const float2* __restrict__ Pml,
                                                  const float* __restrict__ Po,
                                                  float* __restrict__ Ow){
  int gid = blockIdx.x * 256 + threadIdx.x;   // < 131072
  int row = gid >> 5, d = gid & 31;
  float2 ml[NSPLIT_];
  #pragma unroll
  for(int k=0;k<NSPLIT_;k++) ml[k] = Pml[row*NSPLIT_ + k];
  float M = ml[0].x;
  #pragma unroll
  for(int k=1;k<NSPLIT_;k++) M = fmaxf(M, ml[k].x);
  float L = 0.f, o = 0.f;
  #pragma unroll
  for(int k=0;k<NSPLIT_;k++){
    float e = __expf(ml[k].x - M);
    L += ml[k].y * e;
    o += Po[(size_t)(row*NSPLIT_ + k)*32 + d] * e;
  }
  Ow[row*32 + d] = o / L;
}

// ---------------------------------------------------------------- out-proj + GRU + LN + MLP
__global__ __launch_bounds__(256) void gru_mlp(const float* __restrict__ Ain,
    const float* __restrict__ slots_in,
    const float* __restrict__ wo,  const float* __restrict__ bo,
    const float* __restrict__ wihT,const float* __restrict__ bih,
    const float* __restrict__ whhT,const float* __restrict__ bhh,
    const float* __restrict__ w1,  const float* __restrict__ b1,
    const float* __restrict__ w2,  const float* __restrict__ b2,
    const float* __restrict__ gm,  const float* __restrict__ bm,
    float* __restrict__ slots_out){
  __shared__ float xr[4][256], hr[4][256], o2[4][256], hnew[4][256], hid[4][512];
  __shared__ float red[4][8];
  int t = threadIdx.x, r0 = blockIdx.x*4;
  int wv_ = t >> 6, lane = t & 63;
  #pragma unroll
  for(int rr=0;rr<4;rr++){
    int r = r0+rr, b_ = r>>3, s_ = r&7;
    int h = t>>5, d = t&31;
    xr[rr][t] = Ain[((b_*8 + h)*8 + s_)*32 + d];   // un-transpose heads
    hr[rr][t] = slots_in[r*256 + t];
  }
  __syncthreads();
  { // out2 = xr @ wo + bo
    float a0=0,a1=0,a2=0,a3=0;
    for(int d=0; d<256; d++){
      float w = wo[d*256 + t];
      a0 = fmaf(xr[0][d],w,a0); a1 = fmaf(xr[1][d],w,a1);
      a2 = fmaf(xr[2][d],w,a2); a3 = fmaf(xr[3][d],w,a3);
    }
    float bv = bo[t];
    o2[0][t]=a0+bv; o2[1][t]=a1+bv; o2[2][t]=a2+bv; o2[3][t]=a3+bv;
  }
  __syncthreads();
  { // GRU gates
    float ir[4]={}, iz[4]={}, inn[4]={}, hrr[4]={}, hz[4]={}, hn[4]={};
    for(int d=0; d<256; d++){
      float wi0 = wihT[d*768 + t], wi1 = wihT[d*768 + 256 + t], wi2 = wihT[d*768 + 512 + t];
      float wh0 = whhT[d*768 + t], wh1 = whhT[d*768 + 256 + t], wh2 = whhT[d*768 + 512 + t];
      #pragma unroll
      for(int rr=0;rr<4;rr++){
        float xo = o2[rr][d], hh = hr[rr][d];
        ir[rr]  = fmaf(xo,wi0,ir[rr]);  iz[rr] = fmaf(xo,wi1,iz[rr]);  inn[rr] = fmaf(xo,wi2,inn[rr]);
        hrr[rr] = fmaf(hh,wh0,hrr[rr]); hz[rr] = fmaf(hh,wh1,hz[rr]);  hn[rr]  = fmaf(hh,wh2,hn[rr]);
      }
    }
    float bi0 = bih[t], bi1 = bih[256+t], bi2 = bih[512+t];
    float bh0 = bhh[t], bh1 = bhh[256+t], bh2 = bhh[512+t];
    #pragma unroll
    for(int rr=0;rr<4;rr++){
      float rg = 1.f/(1.f + __expf(-(ir[rr]+bi0 + hrr[rr]+bh0)));
      float zg = 1.f/(1.f + __expf(-(iz[rr]+bi1 + hz[rr]+bh1)));
      float ng = tanhf(inn[rr]+bi2 + rg*(hn[rr]+bh2));
      hnew[rr][t] = (1.f - zg)*ng + zg*hr[rr][t];
    }
  }
  __syncthreads();
  // LN(hnew) per row -> m stored in xr (xr is dead)
  #pragma unroll
  for(int rr=0;rr<4;rr++){
    float v = hnew[rr][t];
    float s1=v, s2=v*v;
    #pragma unroll
    for(int o=32;o>=1;o>>=1){ s1 += __shfl_xor(s1,o,64); s2 += __shfl_xor(s2,o,64); }
    if(lane==0){ red[rr][wv_]=s1; red[rr][4+wv_]=s2; }
  }
  __syncthreads();
  {
    float gmt = gm[t], bmt = bm[t];
    #pragma unroll
    for(int rr=0;rr<4;rr++){
      float fs1 = red[rr][0]+red[rr][1]+red[rr][2]+red[rr][3];
      float fs2 = red[rr][4]+red[rr][5]+red[rr][6]+red[rr][7];
      float mean = fs1*(1.f/256.f);
      float var  = fs2*(1.f/256.f) - mean*mean;
      float rstd = rsqrtf(var + EPS_);
      xr[rr][t] = (hnew[rr][t]-mean)*rstd*gmt + bmt;
    }
  }
  __syncthreads();
  { // hid = relu(m @ w1 + b1)
    float c0[4]={}, c1[4]={};
    for(int d=0; d<256; d++){
      float wA = w1[d*512 + t], wB = w1[d*512 + 256 + t];
      #pragma unroll
      for(int rr=0;rr<4;rr++){ float mv = xr[rr][d]; c0[rr]=fmaf(mv,wA,c0[rr]); c1[rr]=fmaf(mv,wB,c1[rr]); }
    }
    float b1a = b1[t], b1b = b1[256+t];
    #pragma unroll
    for(int rr=0;rr<4;rr++){
      hid[rr][t]     = fmaxf(c0[rr]+b1a, 0.f);
      hid[rr][t+256] = fmaxf(c1[rr]+b1b, 0.f);
    }
  }
  __syncthreads();
  { // slots_out = hnew + hid @ w2 + b2
    float a[4]={};
    for(int k=0;k<512;k++){
      float w = w2[k*256 + t];
      #pragma unroll
      for(int rr=0;rr<4;rr++) a[rr] = fmaf(hid[rr][k], w, a[rr]);
    }
    float b2t = b2[t];
    #pragma unroll
    for(int rr=0;rr<4;rr++){
      int r = r0+rr;
      slots_out[r*256 + t] = hnew[rr][t] + a[rr] + b2t;
    }
  }
}

// ----------------------------------------------------------------
extern "C" void kernel_launch(void* const* d_in, const int* in_sizes, int n_in,
                              void* d_out, int out_size, void* d_ws, size_t ws_size,
                              hipStream_t stream){
  const float* inputs = (const float*)d_in[0];
  const float* noise  = (const float*)d_in[1];
  const float* mu     = (const float*)d_in[2];
  const float* lsig   = (const float*)d_in[3];
  const float* wq  = (const float*)d_in[4];  const float* bq  = (const float*)d_in[5];
  const float* wk  = (const float*)d_in[6];  const float* bk  = (const float*)d_in[7];
  const float* wv  = (const float*)d_in[8];  const float* bv  = (const float*)d_in[9];
  const float* wo  = (const float*)d_in[10]; const float* bo  = (const float*)d_in[11];
  const float* wih = (const float*)d_in[12]; const float* bih = (const float*)d_in[13];
  const float* whh = (const float*)d_in[14]; const float* bhh = (const float*)d_in[15];
  const float* w1  = (const float*)d_in[16]; const float* b1  = (const float*)d_in[17];
  const float* w2  = (const float*)d_in[18]; const float* b2  = (const float*)d_in[19];
  const float* g_in= (const float*)d_in[20]; const float* b_in= (const float*)d_in[21];
  const float* g_sl= (const float*)d_in[22]; const float* b_sl= (const float*)d_in[23];
  const float* g_ml= (const float*)d_in[24]; const float* b_ml= (const float*)d_in[25];

  const size_t sz_big = (size_t)M_ * D_ * 2;   // 134,217,728 B each
  size_t need = 3*sz_big + 512*256*2 + 2*(256*768*4) + 3*(512*256*4)
              + 4096*NSPLIT_*8 + (size_t)4096*NSPLIT_*32*4;
  if(ws_size < need) return;

  char* p = (char*)d_ws;
  u16*   xb   = (u16*)p;   p += sz_big;
  u16*   Kp   = (u16*)p;   p += sz_big;
  u16*   Vp   = (u16*)p;   p += sz_big;      // holds V^T [bh][d][n]
  u16*   wkvT = (u16*)p;   p += 512*256*2;
  float* wihT = (float*)p; p += 256*768*4;
  float* whhT = (float*)p; p += 256*768*4;
  float* slots= (float*)p; p += 512*256*4;
  float* Qw   = (float*)p; p += 512*256*4;
  float* Ow   = (float*)p; p += 512*256*4;
  float2* Pml = (float2*)p; p += 4096*NSPLIT_*8;
  float* Po   = (float*)p;  p += (size_t)4096*NSPLIT_*32*4;

  prep_kernel<<<2048, 256, 0, stream>>>(wk, wv, wih, whh, wkvT, wihT, whhT);
  init_slots <<<512, 256, 0, stream>>>(mu, lsig, noise, slots);
  ln_kernel  <<<M_/4, 256, 0, stream>>>(inputs, g_in, b_in, xb);
  kv_gemm    <<<M_/64, 512, 0, stream>>>(xb, wkvT, bk, bv, Kp, Vp);

  for(int it = 0; it < ITERS_; ++it){
    qproj<<<512, 256, 0, stream>>>(slots, g_sl, b_sl, wq, bq, Qw);
    attn_part<<<dim3(512, NSPLIT_), 256, 0, stream>>>(Qw, Kp, Vp, Pml, Po);
    attn_merge<<<512, 256, 0, stream>>>(Pml, Po, Ow);
    float* outp = (it == ITERS_-1) ? (float*)d_out : slots;
    gru_mlp<<<128, 256, 0, stream>>>(Ow, slots, wo, bo, wihT, bih, whhT, bhh,
                                     w1, b1, w2, b2, g_ml, b_ml, outp);
  }
}

// Round 5
// 1108.468 us; speedup vs baseline: 1.1464x; 1.0766x over previous
//
#include <hip/hip_runtime.h>
#include <hip/hip_bf16.h>

#define B_ 64
#define N_ 4096
#define D_ 256
#define S_ 8
#define NH_ 8
#define DK_ 32
#define ITERS_ 3
#define MLPH_ 512
#define EPS_ 1e-5f
#define M_ (B_*N_)          // 262144 rows of x
#define NEG_BIG_ -3.0e38f   // finite sentinel: exp(NEG_BIG_-x) underflows to 0.f
#define NSPLIT_ 4           // attention N-partitions per (b,h)

typedef unsigned short u16;
typedef short bf16x8 __attribute__((ext_vector_type(8)));
typedef float f32x4 __attribute__((ext_vector_type(4)));

__device__ __forceinline__ u16 f2bf(float f){
  unsigned int x = __float_as_uint(f);
  return (u16)((x + 0x7fffu + ((x >> 16) & 1u)) >> 16);   // RNE
}
__device__ __forceinline__ unsigned int pkbf(float a, float b){
  return (unsigned int)f2bf(a) | ((unsigned int)f2bf(b) << 16);
}

// ---------------------------------------------------------------- prep
__global__ void prep_kernel(const float* __restrict__ wk, const float* __restrict__ wv,
                            const float* __restrict__ wih, const float* __restrict__ whh,
                            u16* __restrict__ wkvT, float* __restrict__ wihT,
                            float* __restrict__ whhT){
  int idx = blockIdx.x * 256 + threadIdx.x;
  if(idx < 512*256){
    int n = idx >> 8, k = idx & 255;
    float v = (n < 256) ? wk[k*256 + n] : wv[k*256 + (n-256)];
    wkvT[n*256 + k] = f2bf(v);
    return;
  }
  int i2 = idx - 512*256;
  if(i2 < 196608){           // w_ihT
    int d = i2 / 768, j = i2 - d*768;
    wihT[i2] = wih[j*256 + d];
    return;
  }
  int i3 = i2 - 196608;
  if(i3 < 196608){           // w_hhT
    int d = i3 / 768, j = i3 - d*768;
    whhT[i3] = whh[j*256 + d];
  }
}

// ---------------------------------------------------------------- slot init
__global__ void init_slots(const float* __restrict__ mu, const float* __restrict__ lsig,
                           const float* __restrict__ noise, float* __restrict__ slots){
  int idx = blockIdx.x * 256 + threadIdx.x;   // < 131072
  int d = idx & 255;
  slots[idx] = mu[d] + __expf(lsig[d]) * noise[idx];
}

// ---------------------------------------------------------------- LN(inputs) -> bf16
__global__ __launch_bounds__(256) void ln_kernel(const float* __restrict__ inp,
                                                 const float* __restrict__ g,
                                                 const float* __restrict__ b,
                                                 u16* __restrict__ xb){
  int wave = threadIdx.x >> 6, lane = threadIdx.x & 63;
  int row = blockIdx.x * 4 + wave;
  float4 v = *(const float4*)(inp + (size_t)row*D_ + lane*4);
  float s  = v.x+v.y+v.z+v.w;
  float ss = v.x*v.x + v.y*v.y + v.z*v.z + v.w*v.w;
  #pragma unroll
  for(int o=32;o>=1;o>>=1){ s += __shfl_xor(s,o,64); ss += __shfl_xor(ss,o,64); }
  float mean = s * (1.f/D_);
  float var  = ss * (1.f/D_) - mean*mean;
  float rstd = rsqrtf(var + EPS_);
  float4 gg = *(const float4*)(g + lane*4);
  float4 bb = *(const float4*)(b + lane*4);
  ushort4 o4;
  o4.x = f2bf((v.x-mean)*rstd*gg.x + bb.x);
  o4.y = f2bf((v.y-mean)*rstd*gg.y + bb.y);
  o4.z = f2bf((v.z-mean)*rstd*gg.z + bb.z);
  o4.w = f2bf((v.w-mean)*rstd*gg.w + bb.w);
  *(ushort4*)(xb + (size_t)row*D_ + lane*4) = o4;
}

// ---------------------------------------------------------------- K/V projection GEMM
// K stored row-major [bh][n][32]; V stored TRANSPOSED [bh][d][n].
// Single-barrier main loop: A tile (64 rows x 256 k, 32 KB) staged ONCE via
// global_load_lds with XOR swizzle; B (wkvT, 256 KB, L2-hot) read from global
// with explicit double-buffer prefetch (bA/bB, fully unrolled -> static regs).
// V epilogue: acc -> dead As reused as T[256 d][64 n] (XOR chunk swizzle,
// <=2-way banks) -> full-64B-line global stores of V^T. No V scatter.
__global__ __launch_bounds__(512) void kv_gemm(const u16* __restrict__ xb,
                                               const u16* __restrict__ wkvT,
                                               const float* __restrict__ bk,
                                               const float* __restrict__ bv,
                                               u16* __restrict__ Kp, u16* __restrict__ Vp){
  __shared__ u16 As[64*256];                  // 32 KB (reused as V^T staging)
  int rt = blockIdx.x;                        // 0..4095, 64-row strip
  int tid = threadIdx.x;
  int w = tid >> 6, lane = tid & 63;
  int lr = lane & 15, quad = lane >> 4;

  // ---- stage A tile: each wave issues 4 x 1KB DMA (2 rows each)
  {
    const u16* agp = xb + (size_t)(rt*64)*256;
    int i0 = w*4;
    #pragma unroll
    for(int i=0;i<4;i++){
      int r = 2*(i0+i) + (lane >> 5);
      int c16 = lane & 31;
      __builtin_amdgcn_global_load_lds(
        (const __attribute__((address_space(1))) void*)(agp + (size_t)r*256 + ((c16 ^ (r&7)) << 3)),
        (__attribute__((address_space(3))) void*)(As + (i0+i)*512),
        16, 0, 0);
    }
  }

  f32x4 zf = {0.f,0.f,0.f,0.f};
  f32x4 acc[4][4];
  #pragma unroll
  for(int mt=0;mt<4;mt++)
    #pragma unroll
    for(int nt=0;nt<4;nt++) acc[mt][nt] = zf;

  const u16* bw = wkvT + (size_t)(w*64)*256;  // this wave's 64-col strip of B

  // prefetch B for kc=0 BEFORE the barrier (completes under the DMA wait)
  bf16x8 bA[4], bB[4];
  #pragma unroll
  for(int nt=0;nt<4;nt++)
    bA[nt] = *(const bf16x8*)(bw + (size_t)(nt*16 + lr)*256 + quad*8);

  __syncthreads();                            // A tile ready (vmcnt drained here)

  // ---- barrier-free MFMA loop: 8 k-chunks of 32, B double-buffered
  #pragma unroll
  for(int kc=0; kc<8; kc++){
    if(kc < 7){                               // prefetch next B chunk
      #pragma unroll
      for(int nt=0;nt<4;nt++){
        bf16x8 nb = *(const bf16x8*)(bw + (size_t)(nt*16 + lr)*256 + (kc+1)*32 + quad*8);
        if(kc & 1) bA[nt] = nb; else bB[nt] = nb;
      }
    }
    bf16x8 a[4];
    #pragma unroll
    for(int mt=0;mt<4;mt++){
      int R = mt*16 + lr;
      int chunk = kc*4 + quad;
      int sw = (chunk & 0x18) | ((chunk ^ R) & 7);
      a[mt] = *(const bf16x8*)(As + R*256 + sw*8);
    }
    #pragma unroll
    for(int mt=0;mt<4;mt++)
      #pragma unroll
      for(int nt=0;nt<4;nt++)
        acc[mt][nt] = __builtin_amdgcn_mfma_f32_16x16x32_bf16(
            a[mt], (kc & 1) ? bB[nt] : bA[nt], acc[mt][nt], 0,0,0);
  }

  const int bb = rt >> 6;                 // batch index (strips never straddle)
  const int n0 = (rt & 63) * 64;          // n offset within batch
  u16* T = As;                            // reuse: T[256 d][64 n], XOR-swizzled

  __syncthreads();                        // all As reads done before overwrite

  if(w >= 4){
    // ---- V waves: bias + f2bf + transpose-store into LDS T
    #pragma unroll
    for(int nt=0;nt<4;nt++){
      int d_ = (w-4)*64 + nt*16 + lr;     // 0..255
      float bias = bv[d_];
      int d7 = (d_ & 7) << 3;
      #pragma unroll
      for(int mt=0;mt<4;mt++){
        #pragma unroll
        for(int i=0;i<4;i++){
          int n = mt*16 + quad*4 + i;     // 0..63
          T[d_*64 + (n ^ d7)] = f2bf(acc[mt][nt][i] + bias);
        }
      }
    }
  } else {
    // ---- K waves: compact direct stores
    #pragma unroll
    for(int mt=0;mt<4;mt++){
      #pragma unroll
      for(int nt=0;nt<4;nt++){
        int gc = w*64 + nt*16 + lr;       // 0..255
        int h = gc >> 5, d = gc & 31;
        float bias = bk[gc];
        #pragma unroll
        for(int i=0;i<4;i++){
          int n = n0 + mt*16 + quad*4 + i;
          Kp[((size_t)(bb*8 + h)*4096 + n)*32 + d] = f2bf(acc[mt][nt][i] + bias);
        }
      }
    }
  }
  __syncthreads();
  // ---- all 8 waves: write V^T out as full 64B lines
  {
    int d2 = tid >> 1, half = tid & 1;    // d2: 0..255 col, half: n 32-block
    int h = d2 >> 5, d = d2 & 31;
    int d7 = d2 & 7;
    u16* dst = Vp + ((size_t)(bb*8 + h)*32 + d)*4096 + n0 + half*32;
    #pragma unroll
    for(int j=0;j<4;j++){
      int c = half*4 + j;                 // 16B chunk index in n (0..7)
      *(uint4*)(dst + j*8) = *(const uint4*)(T + d2*64 + ((c ^ d7) << 3));
    }
  }
}

// ---------------------------------------------------------------- LN(slots)+Q proj
__global__ __launch_bounds__(256) void qproj(const float* __restrict__ slots,
                                             const float* __restrict__ g,
                                             const float* __restrict__ b,
                                             const float* __restrict__ wq,
                                             const float* __restrict__ bq,
                                             float* __restrict__ Q){
  __shared__ float sp[256];
  __shared__ float red[8];
  int r = blockIdx.x, t = threadIdx.x;
  float v = slots[r*256 + t];
  float s1 = v, s2 = v*v;
  #pragma unroll
  for(int o=32;o>=1;o>>=1){ s1 += __shfl_xor(s1,o,64); s2 += __shfl_xor(s2,o,64); }
  int wv_ = t >> 6, lane = t & 63;
  if(lane==0){ red[wv_] = s1; red[4+wv_] = s2; }
  __syncthreads();
  float fs1 = red[0]+red[1]+red[2]+red[3];
  float fs2 = red[4]+red[5]+red[6]+red[7];
  float mean = fs1*(1.f/256.f);
  float var  = fs2*(1.f/256.f) - mean*mean;
  float rstd = rsqrtf(var + EPS_);
  sp[t] = (v - mean)*rstd*g[t] + b[t];
  __syncthreads();
  float acc = bq[t];
  for(int d=0; d<256; d++) acc = fmaf(sp[d], wq[d*256 + t], acc);
  int b_ = r >> 3, s_ = r & 7;
  int h = t >> 5, d_ = t & 31;
  Q[((b_*8 + h)*8 + s_)*32 + d_] = acc;
}

// ---------------------------------------------------------------- attention (MFMA, slot-shared)
// grid (512, NSPLIT_); block = 256 (4 waves). Block = (b,h); each wave owns a
// 256-row slice of its 1024-row split and computes ALL 8 slots via MFMA:
//   scores^T: C1[n16][s] = mfma(A=K rows [n x d], B=Q^T [d x s])
//   out^T   : C2[d16][s] = mfma(A=V^T rows [d x n], B=P [n x s])
// Softmax state lives at s = lane&15 in both C1 and C2 layouts -> no cross-lane
// moves for m/l/corr. P is repacked C1->B via 4 packs + 8 shuffles + 4 selects.
// 4 wave-partials merged in LDS -> same Pml/Po format as before (NSPLIT_ parts).
__global__ __launch_bounds__(256) void attn_part(const float* __restrict__ Qw,
                                                 const u16* __restrict__ Kp,
                                                 const u16* __restrict__ Vp,
                                                 float2* __restrict__ Pml,
                                                 float* __restrict__ Po){
  const int bh = blockIdx.x, sp_ = blockIdx.y;
  const int w = threadIdx.x >> 6, lane = threadIdx.x & 63;
  const int c = lane & 15, q = lane >> 4;
  const float scale = 0.17677669529663687f;   // 1/sqrt(32)

  __shared__ float oW[4][8][32];
  __shared__ float mW[4][8], lW[4][8];

  // B1 fragment: Q^T, lane holds Q[s=c][d=8q+e]; zeros for padded slots c>=8
  bf16x8 qf;
  {
    union { u16 u[8]; bf16x8 v; } qq;
    if(c < 8){
      const float4* qp = (const float4*)(Qw + ((size_t)bh*8 + c)*32 + q*8);
      float4 v0 = qp[0], v1 = qp[1];
      qq.u[0]=f2bf(v0.x); qq.u[1]=f2bf(v0.y); qq.u[2]=f2bf(v0.z); qq.u[3]=f2bf(v0.w);
      qq.u[4]=f2bf(v1.x); qq.u[5]=f2bf(v1.y); qq.u[6]=f2bf(v1.z); qq.u[7]=f2bf(v1.w);
    } else {
      #pragma unroll
      for(int e=0;e<8;e++) qq.u[e]=0;
    }
    qf = qq.v;
  }

  const int row0 = sp_*(N_/NSPLIT_) + w*(N_/NSPLIT_/4);     // 256-row sub-slice
  const u16* kb = Kp + (size_t)bh*(N_*DK_) + (size_t)row0*DK_;  // K[n][d]
  const u16* vt = Vp + (size_t)bh*(N_*DK_) + row0;              // V^T[d][n]

  float m = NEG_BIG_, l = 0.f;
  f32x4 acc2[2] = {{0.f,0.f,0.f,0.f},{0.f,0.f,0.f,0.f}};
  const int La = c + 32*(q&1);     // shuffle source lanes for P repack
  const int Lb = La + 16;
  const int thi = q >> 1;

  #pragma unroll 2
  for(int ch=0; ch<8; ch++){                 // 8 chunks of 32 rows
    // A1 fragments: K[row0+ch*32+16t+c][8q..8q+7]  (b128 each)
    bf16x8 kf0 = *(const bf16x8*)(kb + (size_t)(ch*32 +      c)*DK_ + q*8);
    bf16x8 kf1 = *(const bf16x8*)(kb + (size_t)(ch*32 + 16 + c)*DK_ + q*8);
    // A2 fragments: V^T[16t+c][row0+ch*32+8q .. +7]  (b128 each)
    bf16x8 vf0 = *(const bf16x8*)(vt + (size_t)(     c)*N_ + ch*32 + q*8);
    bf16x8 vf1 = *(const bf16x8*)(vt + (size_t)(16 + c)*N_ + ch*32 + q*8);

    f32x4 s0 = {0.f,0.f,0.f,0.f}, s1 = {0.f,0.f,0.f,0.f};
    s0 = __builtin_amdgcn_mfma_f32_16x16x32_bf16(kf0, qf, s0, 0,0,0);
    s1 = __builtin_amdgcn_mfma_f32_16x16x32_bf16(kf1, qf, s1, 0,0,0);

    // lane holds scores for s=c at n = ch*32 + 16t + 4q + r
    float p[8];
    #pragma unroll
    for(int r=0;r<4;r++){ p[r] = s0[r]*scale; p[4+r] = s1[r]*scale; }
    float cm = p[0];
    #pragma unroll
    for(int i=1;i<8;i++) cm = fmaxf(cm, p[i]);
    cm = fmaxf(cm, __shfl_xor(cm, 16, 64));
    cm = fmaxf(cm, __shfl_xor(cm, 32, 64));
    float nm = fmaxf(m, cm);
    float corr = __expf(m - nm);
    m = nm;
    float ps = 0.f;
    #pragma unroll
    for(int i=0;i<8;i++){ p[i] = __expf(p[i] - nm); ps += p[i]; }
    ps += __shfl_xor(ps, 16, 64);
    ps += __shfl_xor(ps, 32, 64);
    l = l*corr + ps;
    #pragma unroll
    for(int r=0;r<4;r++){ acc2[0][r] *= corr; acc2[1][r] *= corr; }

    // repack P (C1 layout) -> B2 fragment: lane needs P[n=8q+e][s=c]
    unsigned int u0 = pkbf(p[0],p[1]), u1 = pkbf(p[2],p[3]);
    unsigned int u2 = pkbf(p[4],p[5]), u3 = pkbf(p[6],p[7]);
    unsigned int a0 = (unsigned int)__shfl((int)u0, La, 64);
    unsigned int a1 = (unsigned int)__shfl((int)u1, La, 64);
    unsigned int a2 = (unsigned int)__shfl((int)u2, La, 64);
    unsigned int a3 = (unsigned int)__shfl((int)u3, La, 64);
    unsigned int b0 = (unsigned int)__shfl((int)u0, Lb, 64);
    unsigned int b1 = (unsigned int)__shfl((int)u1, Lb, 64);
    unsigned int b2 = (unsigned int)__shfl((int)u2, Lb, 64);
    unsigned int b3 = (unsigned int)__shfl((int)u3, Lb, 64);
    union { unsigned int wu[4]; bf16x8 v; } pf;
    pf.wu[0] = thi ? a2 : a0;
    pf.wu[1] = thi ? a3 : a1;
    pf.wu[2] = thi ? b2 : b0;
    pf.wu[3] = thi ? b3 : b1;

    acc2[0] = __builtin_amdgcn_mfma_f32_16x16x32_bf16(vf0, pf.v, acc2[0], 0,0,0);
    acc2[1] = __builtin_amdgcn_mfma_f32_16x16x32_bf16(vf1, pf.v, acc2[1], 0,0,0);
  }

  // wave partials -> LDS.  acc2[t][r] = out^T[d=16t+4q+r][s=c] (unnormalized)
  if(c < 8){
    #pragma unroll
    for(int t=0;t<2;t++)
      #pragma unroll
      for(int r=0;r<4;r++)
        oW[w][c][16*t + 4*q + r] = acc2[t][r];
    if(q == 0){ mW[w][c] = m; lW[w][c] = l; }
  }
  __syncthreads();
  {
    int s = threadIdx.x >> 5, d = threadIdx.x & 31;   // 8 x 32 = 256 threads
    float M = fmaxf(fmaxf(mW[0][s], mW[1][s]), fmaxf(mW[2][s], mW[3][s]));
    float L = 0.f, O = 0.f;
    #pragma unroll
    for(int k=0;k<4;k++){
      float e = __expf(mW[k][s] - M);
      L += lW[k][s]*e;
      O += oW[k][s][d]*e;
    }
    Po[((size_t)(bh*8 + s)*NSPLIT_ + sp_)*32 + d] = O;   // unnormalized
    if(d == 0) Pml[(bh*8 + s)*NSPLIT_ + sp_] = make_float2(M, L);
  }
}

// ---------------------------------------------------------------- merge split partials -> Ow
// one thread per (row, d): row = (bh*8+s) in [0,4096), d in [0,32)
__global__ __launch_bounds__(256) void attn_merge(const float2* __restrict__ Pml,
                                                  const float* __restrict__ Po,
                                                  float* __restrict__ Ow){
  int gid = blockIdx.x * 256 + threadIdx.x;   // < 131072
  int row = gid >> 5, d = gid & 31;
  float2 ml[NSPLIT_];
  #pragma unroll
  for(int k=0;k<NSPLIT_;k++) ml[k] = Pml[row*NSPLIT_ + k];
  float M = ml[0].x;
  #pragma unroll
  for(int k=1;k<NSPLIT_;k++) M = fmaxf(M, ml[k].x);
  float L = 0.f, o = 0.f;
  #pragma unroll
  for(int k=0;k<NSPLIT_;k++){
    float e = __expf(ml[k].x - M);
    L += ml[k].y * e;
    o += Po[(size_t)(row*NSPLIT_ + k)*32 + d] * e;
  }
  Ow[row*32 + d] = o / L;
}

// ---------------------------------------------------------------- out-proj + GRU + LN + MLP
__global__ __launch_bounds__(256) void gru_mlp(const float* __restrict__ Ain,
    const float* __restrict__ slots_in,
    const float* __restrict__ wo,  const float* __restrict__ bo,
    const float* __restrict__ wihT,const float* __restrict__ bih,
    const float* __restrict__ whhT,const float* __restrict__ bhh,
    const float* __restrict__ w1,  const float* __restrict__ b1,
    const float* __restrict__ w2,  const float* __restrict__ b2,
    const float* __restrict__ gm,  const float* __restrict__ bm,
    float* __restrict__ slots_out){
  __shared__ float xr[4][256], hr[4][256], o2[4][256], hnew[4][256], hid[4][512];
  __shared__ float red[4][8];
  int t = threadIdx.x, r0 = blockIdx.x*4;
  int wv_ = t >> 6, lane = t & 63;
  #pragma unroll
  for(int rr=0;rr<4;rr++){
    int r = r0+rr, b_ = r>>3, s_ = r&7;
    int h = t>>5, d = t&31;
    xr[rr][t] = Ain[((b_*8 + h)*8 + s_)*32 + d];   // un-transpose heads
    hr[rr][t] = slots_in[r*256 + t];
  }
  __syncthreads();
  { // out2 = xr @ wo + bo
    float a0=0,a1=0,a2=0,a3=0;
    for(int d=0; d<256; d++){
      float w = wo[d*256 + t];
      a0 = fmaf(xr[0][d],w,a0); a1 = fmaf(xr[1][d],w,a1);
      a2 = fmaf(xr[2][d],w,a2); a3 = fmaf(xr[3][d],w,a3);
    }
    float bv = bo[t];
    o2[0][t]=a0+bv; o2[1][t]=a1+bv; o2[2][t]=a2+bv; o2[3][t]=a3+bv;
  }
  __syncthreads();
  { // GRU gates
    float ir[4]={}, iz[4]={}, inn[4]={}, hrr[4]={}, hz[4]={}, hn[4]={};
    for(int d=0; d<256; d++){
      float wi0 = wihT[d*768 + t], wi1 = wihT[d*768 + 256 + t], wi2 = wihT[d*768 + 512 + t];
      float wh0 = whhT[d*768 + t], wh1 = whhT[d*768 + 256 + t], wh2 = whhT[d*768 + 512 + t];
      #pragma unroll
      for(int rr=0;rr<4;rr++){
        float xo = o2[rr][d], hh = hr[rr][d];
        ir[rr]  = fmaf(xo,wi0,ir[rr]);  iz[rr] = fmaf(xo,wi1,iz[rr]);  inn[rr] = fmaf(xo,wi2,inn[rr]);
        hrr[rr] = fmaf(hh,wh0,hrr[rr]); hz[rr] = fmaf(hh,wh1,hz[rr]);  hn[rr]  = fmaf(hh,wh2,hn[rr]);
      }
    }
    float bi0 = bih[t], bi1 = bih[256+t], bi2 = bih[512+t];
    float bh0 = bhh[t], bh1 = bhh[256+t], bh2 = bhh[512+t];
    #pragma unroll
    for(int rr=0;rr<4;rr++){
      float rg = 1.f/(1.f + __expf(-(ir[rr]+bi0 + hrr[rr]+bh0)));
      float zg = 1.f/(1.f + __expf(-(iz[rr]+bi1 + hz[rr]+bh1)));
      float ng = tanhf(inn[rr]+bi2 + rg*(hn[rr]+bh2));
      hnew[rr][t] = (1.f - zg)*ng + zg*hr[rr][t];
    }
  }
  __syncthreads();
  // LN(hnew) per row -> m stored in xr (xr is dead)
  #pragma unroll
  for(int rr=0;rr<4;rr++){
    float v = hnew[rr][t];
    float s1=v, s2=v*v;
    #pragma unroll
    for(int o=32;o>=1;o>>=1){ s1 += __shfl_xor(s1,o,64); s2 += __shfl_xor(s2,o,64); }
    if(lane==0){ red[rr][wv_]=s1; red[rr][4+wv_]=s2; }
  }
  __syncthreads();
  {
    float gmt = gm[t], bmt = bm[t];
    #pragma unroll
    for(int rr=0;rr<4;rr++){
      float fs1 = red[rr][0]+red[rr][1]+red[rr][2]+red[rr][3];
      float fs2 = red[rr][4]+red[rr][5]+red[rr][6]+red[rr][7];
      float mean = fs1*(1.f/256.f);
      float var  = fs2*(1.f/256.f) - mean*mean;
      float rstd = rsqrtf(var + EPS_);
      xr[rr][t] = (hnew[rr][t]-mean)*rstd*gmt + bmt;
    }
  }
  __syncthreads();
  { // hid = relu(m @ w1 + b1)
    float c0[4]={}, c1[4]={};
    for(int d=0; d<256; d++){
      float wA = w1[d*512 + t], wB = w1[d*512 + 256 + t];
      #pragma unroll
      for(int rr=0;rr<4;rr++){ float mv = xr[rr][d]; c0[rr]=fmaf(mv,wA,c0[rr]); c1[rr]=fmaf(mv,wB,c1[rr]); }
    }
    float b1a = b1[t], b1b = b1[256+t];
    #pragma unroll
    for(int rr=0;rr<4;rr++){
      hid[rr][t]     = fmaxf(c0[rr]+b1a, 0.f);
      hid[rr][t+256] = fmaxf(c1[rr]+b1b, 0.f);
    }
  }
  __syncthreads();
  { // slots_out = hnew + hid @ w2 + b2
    float a[4]={};
    for(int k=0;k<512;k++){
      float w = w2[k*256 + t];
      #pragma unroll
      for(int rr=0;rr<4;rr++) a[rr] = fmaf(hid[rr][k], w, a[rr]);
    }
    float b2t = b2[t];
    #pragma unroll
    for(int rr=0;rr<4;rr++){
      int r = r0+rr;
      slots_out[r*256 + t] = hnew[rr][t] + a[rr] + b2t;
    }
  }
}

// ----------------------------------------------------------------
extern "C" void kernel_launch(void* const* d_in, const int* in_sizes, int n_in,
                              void* d_out, int out_size, void* d_ws, size_t ws_size,
                              hipStream_t stream){
  const float* inputs = (const float*)d_in[0];
  const float* noise  = (const float*)d_in[1];
  const float* mu     = (const float*)d_in[2];
  const float* lsig   = (const float*)d_in[3];
  const float* wq  = (const float*)d_in[4];  const float* bq  = (const float*)d_in[5];
  const float* wk  = (const float*)d_in[6];  const float* bk  = (const float*)d_in[7];
  const float* wv  = (const float*)d_in[8];  const float* bv  = (const float*)d_in[9];
  const float* wo  = (const float*)d_in[10]; const float* bo  = (const float*)d_in[11];
  const float* wih = (const float*)d_in[12]; const float* bih = (const float*)d_in[13];
  const float* whh = (const float*)d_in[14]; const float* bhh = (const float*)d_in[15];
  const float* w1  = (const float*)d_in[16]; const float* b1  = (const float*)d_in[17];
  const float* w2  = (const float*)d_in[18]; const float* b2  = (const float*)d_in[19];
  const float* g_in= (const float*)d_in[20]; const float* b_in= (const float*)d_in[21];
  const float* g_sl= (const float*)d_in[22]; const float* b_sl= (const float*)d_in[23];
  const float* g_ml= (const float*)d_in[24]; const float* b_ml= (const float*)d_in[25];

  const size_t sz_big = (size_t)M_ * D_ * 2;   // 134,217,728 B each
  size_t need = 3*sz_big + 512*256*2 + 2*(256*768*4) + 3*(512*256*4)
              + 4096*NSPLIT_*8 + (size_t)4096*NSPLIT_*32*4;
  if(ws_size < need) return;

  char* p = (char*)d_ws;
  u16*   xb   = (u16*)p;   p += sz_big;
  u16*   Kp   = (u16*)p;   p += sz_big;
  u16*   Vp   = (u16*)p;   p += sz_big;      // holds V^T [bh][d][n]
  u16*   wkvT = (u16*)p;   p += 512*256*2;
  float* wihT = (float*)p; p += 256*768*4;
  float* whhT = (float*)p; p += 256*768*4;
  float* slots= (float*)p; p += 512*256*4;
  float* Qw   = (float*)p; p += 512*256*4;
  float* Ow   = (float*)p; p += 512*256*4;
  float2* Pml = (float2*)p; p += 4096*NSPLIT_*8;
  float* Po   = (float*)p;  p += (size_t)4096*NSPLIT_*32*4;

  prep_kernel<<<2048, 256, 0, stream>>>(wk, wv, wih, whh, wkvT, wihT, whhT);
  init_slots <<<512, 256, 0, stream>>>(mu, lsig, noise, slots);
  ln_kernel  <<<M_/4, 256, 0, stream>>>(inputs, g_in, b_in, xb);
  kv_gemm    <<<M_/64, 512, 0, stream>>>(xb, wkvT, bk, bv, Kp, Vp);

  for(int it = 0; it < ITERS_; ++it){
    qproj<<<512, 256, 0, stream>>>(slots, g_sl, b_sl, wq, bq, Qw);
    attn_part<<<dim3(512, NSPLIT_), 256, 0, stream>>>(Qw, Kp, Vp, Pml, Po);
    attn_merge<<<512, 256, 0, stream>>>(Pml, Po, Ow);
    float* outp = (it == ITERS_-1) ? (float*)d_out : slots;
    gru_mlp<<<128, 256, 0, stream>>>(Ow, slots, wo, bo, wihT, bih, whhT, bhh,
                                     w1, b1, w2, b2, g_ml, b_ml, outp);
  }
}